// Round 6
// baseline (268.820 us; speedup 1.0000x reference)
//
#include <hip/hip_runtime.h>

typedef __attribute__((ext_vector_type(4))) float f32x4;
typedef __attribute__((ext_vector_type(8))) short short8;
typedef __attribute__((ext_vector_type(8))) unsigned short u16x8;
typedef __attribute__((ext_vector_type(4))) unsigned short u16x4;
typedef __attribute__((ext_vector_type(2))) unsigned int u32x2;

#define D_MODEL 1024
#define NHEADS 16
#define T_SEQ 2048
#define M_TOT 4096   // B*T

__device__ __forceinline__ unsigned short f2bf(float f) {
    union { float f; unsigned int u; } v; v.f = f;
    return (unsigned short)((v.u + 0x7fffu + ((v.u >> 16) & 1u)) >> 16);
}
__device__ __forceinline__ float bf2f(unsigned short b) {
    union { unsigned int u; float f; } v; v.u = ((unsigned int)b) << 16;
    return v.f;
}
__device__ __forceinline__ float bcf(unsigned int u) {
    union { unsigned int u; float f; } v; v.u = u; return v.f;
}
// packed f32x2 -> bf16x2 (low = src0, high = src1)
__device__ __forceinline__ unsigned int cvtpk_bf16(float lo, float hi) {
    unsigned int r;
    asm("v_cvt_pk_bf16_f32 %0, %1, %2" : "=v"(r) : "v"(lo), "v"(hi));
    return r;
}

// ---- inline-asm global loads: compiler can neither sink nor hoist these (volatile),
// so the prefetch ISSUE POINT is pinned where written. vmcnt for these is counted
// MANUALLY (compiler doesn't track asm loads). sched_barrier(0) after each wait
// stops the scheduler hoisting dependent MFMAs above the wait (guide rule #18).
#define GLD(dst, base, OFFSTR) \
    asm volatile("global_load_dwordx4 %0, %1, off offset:" OFFSTR \
                 : "=v"(dst) : "v"(base) : "memory")
#define WAITV16() do { asm volatile("s_waitcnt vmcnt(16)" ::: "memory"); \
                       __builtin_amdgcn_sched_barrier(0); } while (0)
#define WAITV0()  do { asm volatile("s_waitcnt vmcnt(0)"  ::: "memory"); \
                       __builtin_amdgcn_sched_barrier(0); } while (0)

// ---------------- convert x fp32 -> bf16 ----------------
__global__ __launch_bounds__(256) void convert_x_kernel(const float* __restrict__ X,
                                                        unsigned short* __restrict__ Xb) {
    const int i = (blockIdx.x * 256 + threadIdx.x) * 4;
    const float4 v = *(const float4*)(X + i);
    u16x4 r;
    r.x = f2bf(v.x); r.y = f2bf(v.y); r.z = f2bf(v.z); r.w = f2bf(v.w);
    *(u16x4*)(Xb + i) = r;
}

// ---------------- 4x W [k][n] fp32 -> Wt [n][k] bf16, batched over z ----------------
__global__ __launch_bounds__(256) void transpose_w_kernel(const float* __restrict__ W0,
                                                          const float* __restrict__ W1,
                                                          const float* __restrict__ W2,
                                                          const float* __restrict__ W3,
                                                          unsigned short* __restrict__ Wt0) {
    __shared__ float tile[64][65];
    const int z = blockIdx.z;
    const float* W = (z == 0) ? W0 : (z == 1) ? W1 : (z == 2) ? W2 : W3;
    unsigned short* Wt = Wt0 + (size_t)z * D_MODEL * D_MODEL;
    const int n0 = blockIdx.x * 64, k0 = blockIdx.y * 64;
    for (int i = threadIdx.x; i < 4096; i += 256) {
        const int r = i >> 6, c = i & 63;
        tile[r][c] = W[(size_t)(k0 + r) * D_MODEL + n0 + c];
    }
    __syncthreads();
    for (int i = threadIdx.x; i < 4096; i += 256) {
        const int r = i >> 6, c = i & 63;  // r: n-local, c: k-local
        Wt[(size_t)(n0 + r) * D_MODEL + k0 + c] = f2bf(tile[c][r]);
    }
}

// ---------------- GEMM: C = A[M][1024] @ W, with Wt[n][k] pre-transposed ----------------
#define TN_G 128
#define BK_G 32
#define BKP_G 36

template<int MI, int OUTMODE>
__global__ __launch_bounds__(256) void gemm_kernel(
    const unsigned short* __restrict__ A,
    const unsigned short* __restrict__ Bt0,
    void* __restrict__ Cout0,
    const float* __restrict__ cosp,
    const float* __restrict__ sinp)
{
    constexpr int TMc = MI * 32;
    constexpr int NA = (TMc * 4) / 256;
    __shared__ unsigned short sA[TMc * BKP_G];
    __shared__ unsigned short sB[TN_G * BKP_G];

    const int tid = threadIdx.x;
    const int wid = tid >> 6;
    const int lane = tid & 63;
    const int quad = lane >> 4;
    const int l16 = lane & 15;
    const int wm = wid >> 1, wn = wid & 1;
    const int m0 = blockIdx.x * TMc, n0 = blockIdx.y * TN_G;
    const int z = blockIdx.z;
    const unsigned short* Bt = Bt0 + (size_t)z * D_MODEL * D_MODEL;

    f32x4 acc[MI][4] = {};

    for (int k0 = 0; k0 < D_MODEL; k0 += BK_G) {
        u16x8 av[NA], bv[2];
        #pragma unroll
        for (int i = 0; i < NA; ++i) {
            const int c = tid + i * 256, r = c >> 2, sg = (c & 3) * 8;
            av[i] = *(const u16x8*)(A + (size_t)(m0 + r) * D_MODEL + k0 + sg);
        }
        #pragma unroll
        for (int i = 0; i < 2; ++i) {
            const int c = tid + i * 256, r = c >> 2, sg = (c & 3) * 8;
            bv[i] = *(const u16x8*)(Bt + (size_t)(n0 + r) * D_MODEL + k0 + sg);
        }
        __syncthreads();
        #pragma unroll
        for (int i = 0; i < NA; ++i) {
            const int c = tid + i * 256, r = c >> 2, sg = (c & 3) * 8;
            *(u16x8*)&sA[r * BKP_G + sg] = av[i];
        }
        #pragma unroll
        for (int i = 0; i < 2; ++i) {
            const int c = tid + i * 256, r = c >> 2, sg = (c & 3) * 8;
            *(u16x8*)&sB[r * BKP_G + sg] = bv[i];
        }
        __syncthreads();

        short8 af[MI], bf[4];
        #pragma unroll
        for (int i = 0; i < MI; ++i)
            af[i] = *(const short8*)&sA[(wm * (MI * 16) + i * 16 + l16) * BKP_G + quad * 8];
        #pragma unroll
        for (int i = 0; i < 4; ++i)
            bf[i] = *(const short8*)&sB[(wn * 64 + i * 16 + l16) * BKP_G + quad * 8];
        #pragma unroll
        for (int mi = 0; mi < MI; ++mi)
            #pragma unroll
            for (int ni = 0; ni < 4; ++ni)
                acc[mi][ni] = __builtin_amdgcn_mfma_f32_16x16x32_bf16(af[mi], bf[ni], acc[mi][ni], 0, 0, 0);
    }

    if constexpr (OUTMODE == 0) {
        float* C = (float*)Cout0;
        #pragma unroll
        for (int mi = 0; mi < MI; ++mi) {
            const int mb = m0 + wm * (MI * 16) + mi * 16 + quad * 4;
            #pragma unroll
            for (int ni = 0; ni < 4; ++ni) {
                const int n = n0 + wn * 64 + ni * 16 + l16;
                #pragma unroll
                for (int r = 0; r < 4; ++r)
                    C[(size_t)(mb + r) * D_MODEL + n] = acc[mi][ni][r];
            }
        }
    } else {
        unsigned short* O = (unsigned short*)Cout0 + (size_t)z * M_TOT * D_MODEL;
        const int h = (n0 + wn * 64) >> 6;   // each wave's 64 cols = exactly one head
        if (z == 2) {
            // V: write transposed Vt[bh][d][t], packed u16x4 over 4 consecutive t
            #pragma unroll
            for (int mi = 0; mi < MI; ++mi) {
                const int mb = m0 + wm * (MI * 16) + mi * 16 + quad * 4;
                const int b = mb >> 11, t = mb & (T_SEQ - 1);
                #pragma unroll
                for (int ni = 0; ni < 4; ++ni) {
                    const int d = ni * 16 + l16;
                    u16x4 pk;
                    #pragma unroll
                    for (int r = 0; r < 4; ++r) pk[r] = f2bf(acc[mi][ni][r]);
                    *(u16x4*)(O + ((size_t)(b * NHEADS + h) * 64 + d) * T_SEQ + t) = pk;
                }
            }
        } else {
            const float qs = (z == 0) ? 0.125f : 1.0f;   // fold 1/sqrt(64) into Q (exact in bf16)
            #pragma unroll
            for (int mi = 0; mi < MI; ++mi) {
                #pragma unroll
                for (int r = 0; r < 4; ++r) {
                    const int m = m0 + wm * (MI * 16) + mi * 16 + quad * 4 + r;
                    const int b = m >> 11, t = m & (T_SEQ - 1);
                    const size_t rowoff = ((size_t)(b * NHEADS + h) * T_SEQ + t) * 64;
                    #pragma unroll
                    for (int ni = 0; ni < 2; ++ni) {
                        const int d = ni * 16 + l16;           // 0..31
                        const float c = cosp[t * 32 + d], s = sinp[t * 32 + d];
                        const float x1 = acc[mi][ni][r], x2 = acc[mi][ni + 2][r];
                        O[rowoff + d]      = f2bf((x1 * c - x2 * s) * qs);
                        O[rowoff + d + 32] = f2bf((x1 * s + x2 * c) * qs);
                    }
                }
            }
        }
    }
}

// ---------------- K row-norm segment maxes: Kseg[bh][8] = max ||k_row|| over 256-row segs ----------------
__global__ __launch_bounds__(256) void kmax_kernel(const unsigned short* __restrict__ Kg,
                                                   float* __restrict__ Kseg) {
    __shared__ float red[4];
    const int seg = blockIdx.x, bh = blockIdx.y;
    const unsigned short* Kp = Kg + ((size_t)bh * T_SEQ + seg * 256) * 64;
    const int row = threadIdx.x;   // one row per thread
    const u16x8* rp = (const u16x8*)(Kp + (size_t)row * 64);
    float s = 0.f;
    #pragma unroll
    for (int c = 0; c < 8; ++c) {
        const u16x8 v = rp[c];
        #pragma unroll
        for (int e = 0; e < 8; ++e) { const float f = bf2f(v[e]); s += f * f; }
    }
    #pragma unroll
    for (int off = 32; off >= 1; off >>= 1) s = fmaxf(s, __shfl_xor(s, off));
    if ((threadIdx.x & 63) == 0) red[threadIdx.x >> 6] = s;
    __syncthreads();
    if (threadIdx.x == 0)
        Kseg[bh * 8 + seg] = __builtin_sqrtf(fmaxf(fmaxf(red[0], red[1]), fmaxf(red[2], red[3])));
}

// ---------------- flash attention (causal): SINGLE-PASS, Cauchy-Schwarz max bound ----------------
// m_hat = ||q_row|| * max_j ||k_j|| >= max s (softmax shift-invariant -> exact math).
// p = exp2(s*log2e - m_hat*log2e) <= 1 structurally.
//
// R6: EXPLICIT SOFTWARE PIPELINE. R2/R4/R5 all plateaued at 103.5us with every pipe
// idle: the compiler voluntarily minimizes VGPRs (68 at cap 128) by SINKING loads to
// their uses, recreating a serial issue->wait->use chain that occupancy can't hide
// (R4 38% occ == R5 22% occ). Fix: inline-asm global_load_dwordx4 (volatile: cannot
// be sunk/hoisted) double-buffered ONE KV-TILE AHEAD, hand-counted s_waitcnt
// vmcnt(16/0) + sched_barrier(0). F0+F1 force 128 regs live -> ~200 VGPR ->
// 2 waves/SIMD, so grid = 256 blocks (1 block/CU, all co-resident), each block
// processes units flat and flat+256 (same bh -> same L2 set; x and x+8; 33 tiles
// each, uniform). Loop vmcnt ledger: in-loop outstanding = {16 (F_cur) before
// prefetch} -> +16 (F_next) -> wait 16 (F_cur done) -> compute. Tail: wait 0.
// No compiler vmem inside the loop (P is LDS; Q/Kseg consumed pre-loop) so the
// manual counts see only our asm loads.
#define LDPP 72    // P row pitch in u16 (144 B: b128-aligned rows)
#define LOG2E 1.44269504f

union alignas(16) AttnSmem {
    unsigned short P[8][2][16 * LDPP];  // [wave][tile(A,B)][16 rows x 72] = 36864 B
    float comb[4][64][34];              // 34816 B: half=1 partials (O 32 + lA + lB)
};

__global__ __launch_bounds__(512, 1) void attn_kernel(
    const unsigned short* __restrict__ Q,    // [bh][t][64] bf16, RoPE'd, pre-scaled 0.125
    const unsigned short* __restrict__ Kg,   // [bh][t][64] bf16, RoPE'd
    const unsigned short* __restrict__ Vt,   // [bh][d][t]  bf16 (transposed)
    const float* __restrict__ Kseg,          // [bh][8] segment maxes of ||k||
    unsigned short* __restrict__ Z)          // [m][h*64+d] bf16
{
    __shared__ AttnSmem sm;

    const int tid = threadIdx.x;
    const int wid = tid >> 6;        // 0..7
    const int w4 = wid & 3;          // row-slice within q-tile
    const int half = wid >> 2;       // 0: even j, 1: odd j
    const int lane = tid & 63;
    const int quad = lane >> 4;
    const int l16 = lane & 15;

    for (int flat = blockIdx.x; flat < 512; flat += 256) {
        // XCD-locality remap: same xcd & SAME bh for both units of a block; x, x+8.
        const int xcd = flat & 7, idx = flat >> 3;
        const int bh = xcd * 4 + (idx & 3);            // 0..31
        const int x = idx >> 2;                        // 0..15 (unit2: +8 via idx+32)

        const int qA = x, qB = 31 - x;
        const int jend = 31 - x;

        const unsigned short* Qp = Q + (size_t)bh * T_SEQ * 64;
        const unsigned short* Kp = Kg + (size_t)bh * T_SEQ * 64;
        const unsigned short* Vp = Vt + (size_t)bh * 64 * T_SEQ;

        // Q frags (B-operand in swapped QK): row = qt*64 + w4*16 + l16, k = ks*32 + quad*8
        short8 aqA[2], aqB[2];
        {
            const unsigned short* qr = Qp + (size_t)(qA * 64 + w4 * 16 + l16) * 64 + quad * 8;
            aqA[0] = *(const short8*)(qr);
            aqA[1] = *(const short8*)(qr + 32);
            qr = Qp + (size_t)(qB * 64 + w4 * 16 + l16) * 64 + quad * 8;
            aqB[0] = *(const short8*)(qr);
            aqB[1] = *(const short8*)(qr + 32);
        }

        float kmx = 0.f;
        #pragma unroll
        for (int i = 0; i < 8; ++i) kmx = fmaxf(kmx, Kseg[bh * 8 + i]);

        float mQA, mQB;
        {
            float nqA = 0.f, nqB = 0.f;
            #pragma unroll
            for (int i = 0; i < 2; ++i)
                #pragma unroll
                for (int e = 0; e < 8; ++e) {
                    const float fa = bf2f((unsigned short)aqA[i][e]);
                    const float fb = bf2f((unsigned short)aqB[i][e]);
                    nqA += fa * fa; nqB += fb * fb;
                }
            nqA += __shfl_xor(nqA, 16); nqA += __shfl_xor(nqA, 32);
            nqB += __shfl_xor(nqB, 16); nqB += __shfl_xor(nqB, 32);
            mQA = __builtin_sqrtf(nqA) * kmx * LOG2E;
            mQB = __builtin_sqrtf(nqB) * kmx * LOG2E;
        }

        // per-lane fragment base addresses
        const unsigned short* Kfb = Kp + (size_t)l16 * 64 + quad * 8;
        const unsigned short* Vfb = Vp + (size_t)l16 * T_SEQ + quad * 8;

        auto tile_pack = [&](f32x4 (&s)[4], float mQ, float& lsum, bool msk,
                             unsigned short* Pw) {
            if (msk) {
                #pragma unroll
                for (int nt = 0; nt < 4; ++nt)
                    #pragma unroll
                    for (int r = 0; r < 4; ++r)
                        if (nt * 16 + quad * 4 + r > w4 * 16 + l16) s[nt][r] = -1e30f;
            }
            #pragma unroll
            for (int nt = 0; nt < 4; ++nt) {
                const float p0 = __builtin_exp2f(s[nt][0] * LOG2E - mQ);
                const float p1 = __builtin_exp2f(s[nt][1] * LOG2E - mQ);
                const float p2 = __builtin_exp2f(s[nt][2] * LOG2E - mQ);
                const float p3 = __builtin_exp2f(s[nt][3] * LOG2E - mQ);
                const unsigned int w0 = cvtpk_bf16(p0, p1);
                const unsigned int w1 = cvtpk_bf16(p2, p3);
                lsum += bcf(w0 << 16) + bcf(w0 & 0xffff0000u)
                      + bcf(w1 << 16) + bcf(w1 & 0xffff0000u);
                *(u32x2*)&Pw[(size_t)l16 * LDPP + nt * 16 + quad * 4] = (u32x2){w0, w1};
            }
        };

        f32x4 oA[4] = {}, oB[4] = {};
        float lA = 0.f, lB = 0.f;
        unsigned short* PwA = &sm.P[wid][0][0];
        unsigned short* PwB = &sm.P[wid][1][0];

        // asm-load one KV tile set (16 x 16B): K = 8 (2 bases x {0,64,2048,2112}B),
        // V = 8 (4 bases x {0,64}B)
        auto LOADF = [&](short8 (&kf)[4][2], short8 (&vf)[4][2], int j) {
            const unsigned short* kb0 = Kfb + (size_t)j * 4096;   // j*64 rows * 64
            const unsigned short* kb1 = kb0 + 2048;               // +32 rows
            GLD(kf[0][0], kb0, "0");    GLD(kf[0][1], kb0, "64");
            GLD(kf[1][0], kb0, "2048"); GLD(kf[1][1], kb0, "2112");
            GLD(kf[2][0], kb1, "0");    GLD(kf[2][1], kb1, "64");
            GLD(kf[3][0], kb1, "2048"); GLD(kf[3][1], kb1, "2112");
            const unsigned short* vb0 = Vfb + (size_t)j * 64;
            const unsigned short* vb1 = vb0 + 16 * T_SEQ;
            const unsigned short* vb2 = vb0 + 32 * T_SEQ;
            const unsigned short* vb3 = vb0 + 48 * T_SEQ;
            GLD(vf[0][0], vb0, "0");    GLD(vf[0][1], vb0, "64");
            GLD(vf[1][0], vb1, "0");    GLD(vf[1][1], vb1, "64");
            GLD(vf[2][0], vb2, "0");    GLD(vf[2][1], vb2, "64");
            GLD(vf[3][0], vb3, "0");    GLD(vf[3][1], vb3, "64");
        };

        auto COMPUTE = [&](short8 (&kf)[4][2], short8 (&vf)[4][2], int j) {
            const bool doA = (j <= x);
            if (doA) {
                f32x4 sA[4] = {};
                #pragma unroll
                for (int nt = 0; nt < 4; ++nt) {
                    sA[nt] = __builtin_amdgcn_mfma_f32_16x16x32_bf16(kf[nt][0], aqA[0], sA[nt], 0, 0, 0);
                    sA[nt] = __builtin_amdgcn_mfma_f32_16x16x32_bf16(kf[nt][1], aqA[1], sA[nt], 0, 0, 0);
                }
                tile_pack(sA, mQA, lA, j == x, PwA);
            }
            f32x4 sB[4] = {};
            #pragma unroll
            for (int nt = 0; nt < 4; ++nt) {
                sB[nt] = __builtin_amdgcn_mfma_f32_16x16x32_bf16(kf[nt][0], aqB[0], sB[nt], 0, 0, 0);
                sB[nt] = __builtin_amdgcn_mfma_f32_16x16x32_bf16(kf[nt][1], aqB[1], sB[nt], 0, 0, 0);
            }
            tile_pack(sB, mQB, lB, j == jend, PwB);
            asm volatile("s_waitcnt lgkmcnt(0)" ::: "memory");

            if (doA) {
                short8 pf0 = *(const short8*)&PwA[(size_t)l16 * LDPP + quad * 8];
                short8 pf1 = *(const short8*)&PwA[(size_t)l16 * LDPP + 32 + quad * 8];
                #pragma unroll
                for (int dt = 0; dt < 4; ++dt) {
                    oA[dt] = __builtin_amdgcn_mfma_f32_16x16x32_bf16(pf0, vf[dt][0], oA[dt], 0, 0, 0);
                    oA[dt] = __builtin_amdgcn_mfma_f32_16x16x32_bf16(pf1, vf[dt][1], oA[dt], 0, 0, 0);
                }
            }
            {
                short8 pf0 = *(const short8*)&PwB[(size_t)l16 * LDPP + quad * 8];
                short8 pf1 = *(const short8*)&PwB[(size_t)l16 * LDPP + 32 + quad * 8];
                #pragma unroll
                for (int dt = 0; dt < 4; ++dt) {
                    oB[dt] = __builtin_amdgcn_mfma_f32_16x16x32_bf16(pf0, vf[dt][0], oB[dt], 0, 0, 0);
                    oB[dt] = __builtin_amdgcn_mfma_f32_16x16x32_bf16(pf1, vf[dt][1], oB[dt], 0, 0, 0);
                }
            }
        };

        // double-buffered pipeline, one tile ahead; wave-uniform branches
        short8 kf0[4][2], vf0[4][2], kf1[4][2], vf1[4][2];
        int j = half;
        LOADF(kf0, vf0, j);
        while (true) {
            int jn = j + 2;
            if (jn <= jend) {
                LOADF(kf1, vf1, jn);
                WAITV16();
                COMPUTE(kf0, vf0, j);
            } else {
                WAITV0();
                COMPUTE(kf0, vf0, j);
                break;
            }
            j = jn; jn = j + 2;
            if (jn <= jend) {
                LOADF(kf0, vf0, jn);
                WAITV16();
                COMPUTE(kf1, vf1, j);
            } else {
                WAITV0();
                COMPUTE(kf1, vf1, j);
                break;
            }
            j = jn;
        }

        // per-lane row totals (row = l16): reduce across quads
        lA += __shfl_xor(lA, 16); lA += __shfl_xor(lA, 32);
        lB += __shfl_xor(lB, 16); lB += __shfl_xor(lB, 32);

        // combine halves (fixed m_hat => additive). 3rd barrier: comb (union'd with P)
        // must be fully consumed before any wave starts the next unit's P writes.
        __syncthreads();
        if (half) {
            float* cb = &sm.comb[w4][lane][0];
            #pragma unroll
            for (int dt = 0; dt < 4; ++dt)
                #pragma unroll
                for (int r = 0; r < 4; ++r) {
                    cb[dt * 4 + r]      = oA[dt][r];
                    cb[16 + dt * 4 + r] = oB[dt][r];
                }
            cb[32] = lA; cb[33] = lB;
        }
        __syncthreads();
        if (!half) {
            const float* cb = &sm.comb[w4][lane][0];
            #pragma unroll
            for (int dt = 0; dt < 4; ++dt)
                #pragma unroll
                for (int r = 0; r < 4; ++r) {
                    oA[dt][r] += cb[dt * 4 + r];
                    oB[dt][r] += cb[16 + dt * 4 + r];
                }
            lA += cb[32]; lB += cb[33];
        }
        __syncthreads();

        if (!half) {
            const float iA = 1.f / lA, iB = 1.f / lB;
            float irA[4], irB[4];
            #pragma unroll
            for (int r = 0; r < 4; ++r) {
                const int src = (lane & 48) | (quad * 4 + r);
                irA[r] = __shfl(iA, src);
                irB[r] = __shfl(iB, src);
            }
            const int h = bh & 15, b = bh >> 4;
            #pragma unroll
            for (int dt = 0; dt < 4; ++dt)
                #pragma unroll
                for (int r = 0; r < 4; ++r) {
                    const int rowA = qA * 64 + w4 * 16 + quad * 4 + r;
                    const int rowB = qB * 64 + w4 * 16 + quad * 4 + r;
                    const int col = h * 64 + dt * 16 + l16;
                    Z[((size_t)b * T_SEQ + rowA) * D_MODEL + col] = f2bf(oA[dt][r] * irA[r]);
                    Z[((size_t)b * T_SEQ + rowB) * D_MODEL + col] = f2bf(oB[dt][r] * irB[r]);
                }
        }
    }
}

// ---------------- launcher ----------------
extern "C" void kernel_launch(void* const* d_in, const int* in_sizes, int n_in,
                              void* d_out, int out_size, void* d_ws, size_t ws_size,
                              hipStream_t stream) {
    const float* x    = (const float*)d_in[0];
    const float* cosp = (const float*)d_in[1];
    const float* sinp = (const float*)d_in[2];
    const float* Wq   = (const float*)d_in[3];
    const float* Wk   = (const float*)d_in[4];
    const float* Wv   = (const float*)d_in[5];
    const float* Wo   = (const float*)d_in[6];

    char* w = (char*)d_ws;
    unsigned short* xb  = (unsigned short*)w; w += (size_t)M_TOT * D_MODEL * 2;    // 8 MB
    unsigned short* wt  = (unsigned short*)w; w += (size_t)4 * D_MODEL * D_MODEL * 2; // 8 MB (q,k,v,o)
    unsigned short* Qb  = (unsigned short*)w; w += (size_t)M_TOT * D_MODEL * 2;    // 8 MB
    unsigned short* Kb  = (unsigned short*)w; w += (size_t)M_TOT * D_MODEL * 2;
    unsigned short* Vtb = (unsigned short*)w; w += (size_t)M_TOT * D_MODEL * 2;    // [bh][d][t]
    unsigned short* Zb  = (unsigned short*)w; w += (size_t)M_TOT * D_MODEL * 2;
    float*          Ks  = (float*)w;          w += 32 * 8 * sizeof(float);         // Kseg[bh][8]

    convert_x_kernel<<<(M_TOT * D_MODEL) / 1024, 256, 0, stream>>>(x, xb);
    transpose_w_kernel<<<dim3(16, 16, 4), 256, 0, stream>>>(Wq, Wk, Wv, Wo, wt);

    // fused QKV projection; epilogue: z=0 Q(RoPE,*0.125), z=1 K(RoPE), z=2 V(transposed)
    gemm_kernel<4, 1><<<dim3(M_TOT / 128, D_MODEL / 128, 3), 256, 0, stream>>>(
        xb, wt, (void*)Qb, cosp, sinp);

    kmax_kernel<<<dim3(8, 32), 256, 0, stream>>>(Kb, Ks);

    // 256 blocks (1/CU, co-resident), each runs units flat and flat+256
    attn_kernel<<<256, 512, 0, stream>>>(Qb, Kb, Vtb, Ks, Zb);

    // out projection -> fp32 d_out
    gemm_kernel<2, 0><<<dim3(M_TOT / 64, D_MODEL / 128, 1), 256, 0, stream>>>(
        Zb, wt + (size_t)3 * D_MODEL * D_MODEL, d_out, nullptr, nullptr);
}

// Round 8
// 220.186 us; speedup vs baseline: 1.2209x; 1.2209x over previous
//
#include <hip/hip_runtime.h>

typedef __attribute__((ext_vector_type(4))) float f32x4;
typedef __attribute__((ext_vector_type(8))) short short8;
typedef __attribute__((ext_vector_type(8))) unsigned short u16x8;
typedef __attribute__((ext_vector_type(4))) unsigned short u16x4;
typedef __attribute__((ext_vector_type(2))) unsigned int u32x2;

#define D_MODEL 1024
#define NHEADS 16
#define T_SEQ 2048
#define M_TOT 4096   // B*T

__device__ __forceinline__ unsigned short f2bf(float f) {
    union { float f; unsigned int u; } v; v.f = f;
    return (unsigned short)((v.u + 0x7fffu + ((v.u >> 16) & 1u)) >> 16);
}
__device__ __forceinline__ float bf2f(unsigned short b) {
    union { unsigned int u; float f; } v; v.u = ((unsigned int)b) << 16;
    return v.f;
}
__device__ __forceinline__ float bcf(unsigned int u) {
    union { unsigned int u; float f; } v; v.u = u; return v.f;
}
// packed f32x2 -> bf16x2 (low = src0, high = src1)
__device__ __forceinline__ unsigned int cvtpk_bf16(float lo, float hi) {
    unsigned int r;
    asm("v_cvt_pk_bf16_f32 %0, %1, %2" : "=v"(r) : "v"(lo), "v"(hi));
    return r;
}

// volatile asm load: issue point pinned (cannot be sunk/hoisted by the compiler)
#define GLD0(dst, addr) \
    asm volatile("global_load_dwordx4 %0, %1, off" : "=v"(dst) : "v"(addr) : "memory")
// wait all asm loads done, and fence the scheduler (guide rule #18)
#define WAITV0() do { asm volatile("s_waitcnt vmcnt(0)" ::: "memory"); \
                      __builtin_amdgcn_sched_barrier(0); } while (0)
// raw barrier: drain LDS only (NOT vmcnt -> in-flight prefetch survives the barrier)
#define LBAR() do { asm volatile("s_waitcnt lgkmcnt(0)" ::: "memory"); \
                    __builtin_amdgcn_s_barrier(); \
                    __builtin_amdgcn_sched_barrier(0); } while (0)

// ---------------- convert x fp32 -> bf16 ----------------
__global__ __launch_bounds__(256) void convert_x_kernel(const float* __restrict__ X,
                                                        unsigned short* __restrict__ Xb) {
    const int i = (blockIdx.x * 256 + threadIdx.x) * 4;
    const float4 v = *(const float4*)(X + i);
    u16x4 r;
    r.x = f2bf(v.x); r.y = f2bf(v.y); r.z = f2bf(v.z); r.w = f2bf(v.w);
    *(u16x4*)(Xb + i) = r;
}

// ---------------- 4x W [k][n] fp32 -> Wt [n][k] bf16, batched over z ----------------
__global__ __launch_bounds__(256) void transpose_w_kernel(const float* __restrict__ W0,
                                                          const float* __restrict__ W1,
                                                          const float* __restrict__ W2,
                                                          const float* __restrict__ W3,
                                                          unsigned short* __restrict__ Wt0) {
    __shared__ float tile[64][65];
    const int z = blockIdx.z;
    const float* W = (z == 0) ? W0 : (z == 1) ? W1 : (z == 2) ? W2 : W3;
    unsigned short* Wt = Wt0 + (size_t)z * D_MODEL * D_MODEL;
    const int n0 = blockIdx.x * 64, k0 = blockIdx.y * 64;
    for (int i = threadIdx.x; i < 4096; i += 256) {
        const int r = i >> 6, c = i & 63;
        tile[r][c] = W[(size_t)(k0 + r) * D_MODEL + n0 + c];
    }
    __syncthreads();
    for (int i = threadIdx.x; i < 4096; i += 256) {
        const int r = i >> 6, c = i & 63;  // r: n-local, c: k-local
        Wt[(size_t)(n0 + r) * D_MODEL + k0 + c] = f2bf(tile[c][r]);
    }
}

// ---------------- GEMM: C = A[M][1024] @ W, with Wt[n][k] pre-transposed ----------------
#define TN_G 128
#define BK_G 32
#define BKP_G 36

template<int MI, int OUTMODE>
__global__ __launch_bounds__(256) void gemm_kernel(
    const unsigned short* __restrict__ A,
    const unsigned short* __restrict__ Bt0,
    void* __restrict__ Cout0,
    const float* __restrict__ cosp,
    const float* __restrict__ sinp)
{
    constexpr int TMc = MI * 32;
    constexpr int NA = (TMc * 4) / 256;
    __shared__ unsigned short sA[TMc * BKP_G];
    __shared__ unsigned short sB[TN_G * BKP_G];

    const int tid = threadIdx.x;
    const int wid = tid >> 6;
    const int lane = tid & 63;
    const int quad = lane >> 4;
    const int l16 = lane & 15;
    const int wm = wid >> 1, wn = wid & 1;
    const int m0 = blockIdx.x * TMc, n0 = blockIdx.y * TN_G;
    const int z = blockIdx.z;
    const unsigned short* Bt = Bt0 + (size_t)z * D_MODEL * D_MODEL;

    f32x4 acc[MI][4] = {};

    for (int k0 = 0; k0 < D_MODEL; k0 += BK_G) {
        u16x8 av[NA], bv[2];
        #pragma unroll
        for (int i = 0; i < NA; ++i) {
            const int c = tid + i * 256, r = c >> 2, sg = (c & 3) * 8;
            av[i] = *(const u16x8*)(A + (size_t)(m0 + r) * D_MODEL + k0 + sg);
        }
        #pragma unroll
        for (int i = 0; i < 2; ++i) {
            const int c = tid + i * 256, r = c >> 2, sg = (c & 3) * 8;
            bv[i] = *(const u16x8*)(Bt + (size_t)(n0 + r) * D_MODEL + k0 + sg);
        }
        __syncthreads();
        #pragma unroll
        for (int i = 0; i < NA; ++i) {
            const int c = tid + i * 256, r = c >> 2, sg = (c & 3) * 8;
            *(u16x8*)&sA[r * BKP_G + sg] = av[i];
        }
        #pragma unroll
        for (int i = 0; i < 2; ++i) {
            const int c = tid + i * 256, r = c >> 2, sg = (c & 3) * 8;
            *(u16x8*)&sB[r * BKP_G + sg] = bv[i];
        }
        __syncthreads();

        short8 af[MI], bf[4];
        #pragma unroll
        for (int i = 0; i < MI; ++i)
            af[i] = *(const short8*)&sA[(wm * (MI * 16) + i * 16 + l16) * BKP_G + quad * 8];
        #pragma unroll
        for (int i = 0; i < 4; ++i)
            bf[i] = *(const short8*)&sB[(wn * 64 + i * 16 + l16) * BKP_G + quad * 8];
        #pragma unroll
        for (int mi = 0; mi < MI; ++mi)
            #pragma unroll
            for (int ni = 0; ni < 4; ++ni)
                acc[mi][ni] = __builtin_amdgcn_mfma_f32_16x16x32_bf16(af[mi], bf[ni], acc[mi][ni], 0, 0, 0);
    }

    if constexpr (OUTMODE == 0) {
        float* C = (float*)Cout0;
        #pragma unroll
        for (int mi = 0; mi < MI; ++mi) {
            const int mb = m0 + wm * (MI * 16) + mi * 16 + quad * 4;
            #pragma unroll
            for (int ni = 0; ni < 4; ++ni) {
                const int n = n0 + wn * 64 + ni * 16 + l16;
                #pragma unroll
                for (int r = 0; r < 4; ++r)
                    C[(size_t)(mb + r) * D_MODEL + n] = acc[mi][ni][r];
            }
        }
    } else {
        unsigned short* O = (unsigned short*)Cout0 + (size_t)z * M_TOT * D_MODEL;
        const int h = (n0 + wn * 64) >> 6;   // each wave's 64 cols = exactly one head
        if (z == 2) {
            // V: write transposed Vt[bh][d][t], packed u16x4 over 4 consecutive t
            #pragma unroll
            for (int mi = 0; mi < MI; ++mi) {
                const int mb = m0 + wm * (MI * 16) + mi * 16 + quad * 4;
                const int b = mb >> 11, t = mb & (T_SEQ - 1);
                #pragma unroll
                for (int ni = 0; ni < 4; ++ni) {
                    const int d = ni * 16 + l16;
                    u16x4 pk;
                    #pragma unroll
                    for (int r = 0; r < 4; ++r) pk[r] = f2bf(acc[mi][ni][r]);
                    *(u16x4*)(O + ((size_t)(b * NHEADS + h) * 64 + d) * T_SEQ + t) = pk;
                }
            }
        } else {
            const float qs = (z == 0) ? 0.125f : 1.0f;   // fold 1/sqrt(64) into Q (exact in bf16)
            #pragma unroll
            for (int mi = 0; mi < MI; ++mi) {
                #pragma unroll
                for (int r = 0; r < 4; ++r) {
                    const int m = m0 + wm * (MI * 16) + mi * 16 + quad * 4 + r;
                    const int b = m >> 11, t = m & (T_SEQ - 1);
                    const size_t rowoff = ((size_t)(b * NHEADS + h) * T_SEQ + t) * 64;
                    #pragma unroll
                    for (int ni = 0; ni < 2; ++ni) {
                        const int d = ni * 16 + l16;           // 0..31
                        const float c = cosp[t * 32 + d], s = sinp[t * 32 + d];
                        const float x1 = acc[mi][ni][r], x2 = acc[mi][ni + 2][r];
                        O[rowoff + d]      = f2bf((x1 * c - x2 * s) * qs);
                        O[rowoff + d + 32] = f2bf((x1 * s + x2 * c) * qs);
                    }
                }
            }
        }
    }
}

// ---------------- K row-norm segment maxes: Kseg[bh][8] = max ||k_row|| over 256-row segs ----------------
__global__ __launch_bounds__(256) void kmax_kernel(const unsigned short* __restrict__ Kg,
                                                   float* __restrict__ Kseg) {
    __shared__ float red[4];
    const int seg = blockIdx.x, bh = blockIdx.y;
    const unsigned short* Kp = Kg + ((size_t)bh * T_SEQ + seg * 256) * 64;
    const int row = threadIdx.x;   // one row per thread
    const u16x8* rp = (const u16x8*)(Kp + (size_t)row * 64);
    float s = 0.f;
    #pragma unroll
    for (int c = 0; c < 8; ++c) {
        const u16x8 v = rp[c];
        #pragma unroll
        for (int e = 0; e < 8; ++e) { const float f = bf2f(v[e]); s += f * f; }
    }
    #pragma unroll
    for (int off = 32; off >= 1; off >>= 1) s = fmaxf(s, __shfl_xor(s, off));
    if ((threadIdx.x & 63) == 0) red[threadIdx.x >> 6] = s;
    __syncthreads();
    if (threadIdx.x == 0)
        Kseg[bh * 8 + seg] = __builtin_sqrtf(fmaxf(fmaxf(red[0], red[1]), fmaxf(red[2], red[3])));
}

// ---------------- flash attention (causal): SINGLE-PASS, Cauchy-Schwarz max bound ----------------
// m_hat = ||q_row|| * max_j ||k_j|| >= max s (softmax shift-invariant -> exact math).
// p = exp2(s*log2e - m_hat*log2e) <= 1 structurally.
//
// R8 = R7 with the compile fix (LDS store via short8*, not u16x8*).
// COOPERATIVE LDS STAGING. R2/R4/R5/R6 all plateau at 103-110us, invariant to
// occupancy (8 vs 16 w/CU) and scheduling (compiler vs asm pipeline) with all pipes
// idle -> VMEM REQUEST-THROUGHPUT bound: per wave-iteration 16 strided fragment
// gathers x 16 discontiguous 64B lines each, DUPLICATED by the 4 w4-waves of a half
// (~3136 VMEM instr/CU => ~79cyc/instr serialized = the 1265 cyc/wave-iter plateau).
// Fix: per round, the whole block stages K/V[j0],K/V[j1] (32KB) with 4 CONTIGUOUS
// 16B loads per thread (16x fewer VMEM instrs, no duplication), fragments read from
// LDS with XOR swizzle (slot ^= row&7; row-major [64][128B] would be 16-way conflict).
// Staging: volatile-asm loads issued at round start (pinned), vmcnt(0)+write at round
// end -> HBM/L2 latency hidden under compute. Raw s_barrier + lgkmcnt(0) (NOT
// __syncthreads: its vmcnt(0) drain would kill the in-flight prefetch). Single P
// buffer per wave (pack-A -> read-A -> pack-B -> read-B) to fit LDS in 52KB ->
// 2 blocks/CU, 16 waves/CU at (512,2) [cap law: 256/arg, measured R1/R2/R3].
#define LDPP 72    // P row pitch in u16 (144 B: b128-aligned rows)
#define LOG2E 1.44269504f

struct AttnSmem {
    union {
        unsigned short kv[4][4096];  // [K0,V0,K1,V1][row*64 + swz-slot*8] = 32768 B
        float comb[4][64][34];       // 34816 B: half=1 partials (O 32 + lA + lB)
    } u;
    unsigned short P[8][16 * LDPP];  // per-wave single P tile = 18432 B
};

__global__ __launch_bounds__(512, 2) void attn_kernel(
    const unsigned short* __restrict__ Q,    // [bh][t][64] bf16, RoPE'd, pre-scaled 0.125
    const unsigned short* __restrict__ Kg,   // [bh][t][64] bf16, RoPE'd
    const unsigned short* __restrict__ Vt,   // [bh][d][t]  bf16 (transposed)
    const float* __restrict__ Kseg,          // [bh][8] segment maxes of ||k||
    unsigned short* __restrict__ Z)          // [m][h*64+d] bf16
{
    __shared__ AttnSmem sm;

    const int tid = threadIdx.x;
    const int wid = tid >> 6;        // 0..7
    const int w4 = wid & 3;          // row-slice within q-tile
    const int half = wid >> 2;       // 0: even j, 1: odd j
    const int lane = tid & 63;
    const int quad = lane >> 4;
    const int l16 = lane & 15;
    const int srow = tid >> 3;       // staging row 0..63
    const int sslot = tid & 7;       // staging 16B slot
    const int wslot = sslot ^ (srow & 7);          // swizzled slot
    const int sxK = (quad ^ (l16 & 7)) << 3;       // frag-read swizzled elem offset (ks=0)

    // XCD-locality remap (bijective): flat%8 selects XCD; each XCD owns 4 whole bh.
    const int flat = blockIdx.x + 16 * blockIdx.y;     // 0..511
    const int xcd = flat & 7, idx = flat >> 3;         // idx 0..63
    const int bh = xcd * 4 + (idx & 3);                // 0..31
    const int x = idx >> 2;                            // 0..15

    const int qA = x, qB = 31 - x;       // paired q-tiles: 33 tiles/block, constant
    const int jend = 31 - x;             // kv tiles 0..jend cover both

    const unsigned short* Qp = Q + (size_t)bh * T_SEQ * 64;
    const unsigned short* Kp = Kg + (size_t)bh * T_SEQ * 64;
    const unsigned short* Vp = Vt + (size_t)bh * 64 * T_SEQ;

    // Q frags (B-operand in swapped QK): row = qt*64 + w4*16 + l16, k = ks*32 + quad*8
    short8 aqA[2], aqB[2];
    {
        const unsigned short* qr = Qp + (size_t)(qA * 64 + w4 * 16 + l16) * 64 + quad * 8;
        aqA[0] = *(const short8*)(qr);
        aqA[1] = *(const short8*)(qr + 32);
        qr = Qp + (size_t)(qB * 64 + w4 * 16 + l16) * 64 + quad * 8;
        aqB[0] = *(const short8*)(qr);
        aqB[1] = *(const short8*)(qr + 32);
    }

    // max bound: per-lane scalar for q-row l16 (swapped layout: lane = q-row)
    float kmx = 0.f;
    #pragma unroll
    for (int i = 0; i < 8; ++i) kmx = fmaxf(kmx, Kseg[bh * 8 + i]);

    float mQA, mQB;
    {
        float nqA = 0.f, nqB = 0.f;
        #pragma unroll
        for (int i = 0; i < 2; ++i)
            #pragma unroll
            for (int e = 0; e < 8; ++e) {
                const float fa = bf2f((unsigned short)aqA[i][e]);
                const float fb = bf2f((unsigned short)aqB[i][e]);
                nqA += fa * fa; nqB += fb * fb;
            }
        nqA += __shfl_xor(nqA, 16); nqA += __shfl_xor(nqA, 32);
        nqB += __shfl_xor(nqB, 16); nqB += __shfl_xor(nqB, 32);
        mQA = __builtin_sqrtf(nqA) * kmx * LOG2E;
        mQB = __builtin_sqrtf(nqB) * kmx * LOG2E;
    }

    auto tile_pack = [&](f32x4 (&s)[4], float mQ, float& lsum, bool msk,
                         unsigned short* Pw) {
        if (msk) {
            #pragma unroll
            for (int nt = 0; nt < 4; ++nt)
                #pragma unroll
                for (int r = 0; r < 4; ++r)
                    if (nt * 16 + quad * 4 + r > w4 * 16 + l16) s[nt][r] = -1e30f;
        }
        #pragma unroll
        for (int nt = 0; nt < 4; ++nt) {
            const float p0 = __builtin_exp2f(s[nt][0] * LOG2E - mQ);
            const float p1 = __builtin_exp2f(s[nt][1] * LOG2E - mQ);
            const float p2 = __builtin_exp2f(s[nt][2] * LOG2E - mQ);
            const float p3 = __builtin_exp2f(s[nt][3] * LOG2E - mQ);
            const unsigned int w0 = cvtpk_bf16(p0, p1);
            const unsigned int w1 = cvtpk_bf16(p2, p3);
            lsum += bcf(w0 << 16) + bcf(w0 & 0xffff0000u)
                  + bcf(w1 << 16) + bcf(w1 & 0xffff0000u);
            *(u32x2*)&Pw[(size_t)l16 * LDPP + nt * 16 + quad * 4] = (u32x2){w0, w1};
        }
    };

    f32x4 oA[4] = {}, oB[4] = {};
    float lA = 0.f, lB = 0.f;
    unsigned short* Pw = &sm.P[wid][0];
    const unsigned short* sKb = &sm.u.kv[half * 2][0];
    const unsigned short* sVb = &sm.u.kv[half * 2 + 1][0];

    short8 stg[4];
    auto ISSUE = [&](int t) {   // 4 contiguous 16B loads per thread (pinned issue)
        const int j0 = 2 * t, j1 = j0 + 1;
        GLD0(stg[0], Kp + (size_t)j0 * 4096 + tid * 8);
        GLD0(stg[1], Vp + (size_t)srow * 2048 + j0 * 64 + sslot * 8);
        GLD0(stg[2], Kp + (size_t)j1 * 4096 + tid * 8);
        GLD0(stg[3], Vp + (size_t)srow * 2048 + j1 * 64 + sslot * 8);
    };
    auto WRITE = [&] {          // swizzled LDS store of the staged 64B
        const int dst = srow * 64 + (wslot << 3);
        *(short8*)&sm.u.kv[0][dst] = stg[0];
        *(short8*)&sm.u.kv[1][dst] = stg[1];
        *(short8*)&sm.u.kv[2][dst] = stg[2];
        *(short8*)&sm.u.kv[3][dst] = stg[3];
    };

    auto COMPUTE = [&](int j) {
        if (j > jend) return;            // last round: odd half may be inactive
        const bool doA = (j <= x);
        f32x4 sA[4] = {}, sB[4] = {};
        #pragma unroll
        for (int nt = 0; nt < 4; ++nt) {
            const int rb = (nt * 16 + l16) * 64;
            const short8 k0 = *(const short8*)&sKb[rb + sxK];
            const short8 k1 = *(const short8*)&sKb[rb + (sxK ^ 32)];
            if (doA) {
                sA[nt] = __builtin_amdgcn_mfma_f32_16x16x32_bf16(k0, aqA[0], sA[nt], 0, 0, 0);
                sA[nt] = __builtin_amdgcn_mfma_f32_16x16x32_bf16(k1, aqA[1], sA[nt], 0, 0, 0);
            }
            sB[nt] = __builtin_amdgcn_mfma_f32_16x16x32_bf16(k0, aqB[0], sB[nt], 0, 0, 0);
            sB[nt] = __builtin_amdgcn_mfma_f32_16x16x32_bf16(k1, aqB[1], sB[nt], 0, 0, 0);
        }
        short8 pfA0 = {}, pfA1 = {};
        if (doA) {
            tile_pack(sA, mQA, lA, j == x, Pw);
            asm volatile("s_waitcnt lgkmcnt(0)" ::: "memory");
            pfA0 = *(const short8*)&Pw[(size_t)l16 * LDPP + quad * 8];
            pfA1 = *(const short8*)&Pw[(size_t)l16 * LDPP + 32 + quad * 8];
        }
        tile_pack(sB, mQB, lB, j == jend, Pw);
        asm volatile("s_waitcnt lgkmcnt(0)" ::: "memory");
        const short8 pfB0 = *(const short8*)&Pw[(size_t)l16 * LDPP + quad * 8];
        const short8 pfB1 = *(const short8*)&Pw[(size_t)l16 * LDPP + 32 + quad * 8];
        #pragma unroll
        for (int dt = 0; dt < 4; ++dt) {
            const int rb = (dt * 16 + l16) * 64;
            const short8 v0 = *(const short8*)&sVb[rb + sxK];
            const short8 v1 = *(const short8*)&sVb[rb + (sxK ^ 32)];
            if (doA) {
                oA[dt] = __builtin_amdgcn_mfma_f32_16x16x32_bf16(pfA0, v0, oA[dt], 0, 0, 0);
                oA[dt] = __builtin_amdgcn_mfma_f32_16x16x32_bf16(pfA1, v1, oA[dt], 0, 0, 0);
            }
            oB[dt] = __builtin_amdgcn_mfma_f32_16x16x32_bf16(pfB0, v0, oB[dt], 0, 0, 0);
            oB[dt] = __builtin_amdgcn_mfma_f32_16x16x32_bf16(pfB1, v1, oB[dt], 0, 0, 0);
        }
    };

    // ---- staged pipeline: issue(t+1) early, compute(t), write(t+1) late ----
    const int nr = (jend >> 1) + 1;      // block-uniform round count
    ISSUE(0);
    WAITV0();
    WRITE();
    LBAR();
    for (int t = 0; t < nr; ++t) {
        const bool more = (t + 1 < nr);
        if (more) ISSUE(t + 1);
        COMPUTE(2 * t + half);
        LBAR();                          // all reads of kv done
        if (more) {
            WAITV0();                    // staged data arrived (flew during compute)
            WRITE();
            LBAR();                      // writes visible before next compute
        }
    }

    // per-lane row totals (row = l16): reduce across quads
    lA += __shfl_xor(lA, 16); lA += __shfl_xor(lA, 32);
    lB += __shfl_xor(lB, 16); lB += __shfl_xor(lB, 32);

    // combine halves: fixed m_hat => partials add directly (no rescale).
    // __syncthreads (full drain) is fine here: nothing in flight.
    __syncthreads();
    if (half) {
        float* cb = &sm.u.comb[w4][lane][0];
        #pragma unroll
        for (int dt = 0; dt < 4; ++dt)
            #pragma unroll
            for (int r = 0; r < 4; ++r) {
                cb[dt * 4 + r]      = oA[dt][r];
                cb[16 + dt * 4 + r] = oB[dt][r];
            }
        cb[32] = lA; cb[33] = lB;
    }
    __syncthreads();
    if (half) return;

    {
        const float* cb = &sm.u.comb[w4][lane][0];
        #pragma unroll
        for (int dt = 0; dt < 4; ++dt)
            #pragma unroll
            for (int r = 0; r < 4; ++r) {
                oA[dt][r] += cb[dt * 4 + r];
                oB[dt][r] += cb[16 + dt * 4 + r];
            }
        lA += cb[32]; lB += cb[33];
    }

    // invert per-lane (row l16), then gather to C-rows (quad*4+r)
    const float iA = 1.f / lA, iB = 1.f / lB;
    float irA[4], irB[4];
    #pragma unroll
    for (int r = 0; r < 4; ++r) {
        const int src = (lane & 48) | (quad * 4 + r);
        irA[r] = __shfl(iA, src);
        irB[r] = __shfl(iB, src);
    }

    // epilogue: normalize and write
    const int h = bh & 15, b = bh >> 4;
    #pragma unroll
    for (int dt = 0; dt < 4; ++dt)
        #pragma unroll
        for (int r = 0; r < 4; ++r) {
            const int rowA = qA * 64 + w4 * 16 + quad * 4 + r;
            const int rowB = qB * 64 + w4 * 16 + quad * 4 + r;
            const int col = h * 64 + dt * 16 + l16;
            Z[((size_t)b * T_SEQ + rowA) * D_MODEL + col] = f2bf(oA[dt][r] * irA[r]);
            Z[((size_t)b * T_SEQ + rowB) * D_MODEL + col] = f2bf(oB[dt][r] * irB[r]);
        }
}

// ---------------- launcher ----------------
extern "C" void kernel_launch(void* const* d_in, const int* in_sizes, int n_in,
                              void* d_out, int out_size, void* d_ws, size_t ws_size,
                              hipStream_t stream) {
    const float* x    = (const float*)d_in[0];
    const float* cosp = (const float*)d_in[1];
    const float* sinp = (const float*)d_in[2];
    const float* Wq   = (const float*)d_in[3];
    const float* Wk   = (const float*)d_in[4];
    const float* Wv   = (const float*)d_in[5];
    const float* Wo   = (const float*)d_in[6];

    char* w = (char*)d_ws;
    unsigned short* xb  = (unsigned short*)w; w += (size_t)M_TOT * D_MODEL * 2;    // 8 MB
    unsigned short* wt  = (unsigned short*)w; w += (size_t)4 * D_MODEL * D_MODEL * 2; // 8 MB (q,k,v,o)
    unsigned short* Qb  = (unsigned short*)w; w += (size_t)M_TOT * D_MODEL * 2;    // 8 MB
    unsigned short* Kb  = (unsigned short*)w; w += (size_t)M_TOT * D_MODEL * 2;
    unsigned short* Vtb = (unsigned short*)w; w += (size_t)M_TOT * D_MODEL * 2;    // [bh][d][t]
    unsigned short* Zb  = (unsigned short*)w; w += (size_t)M_TOT * D_MODEL * 2;
    float*          Ks  = (float*)w;          w += 32 * 8 * sizeof(float);         // Kseg[bh][8]

    convert_x_kernel<<<(M_TOT * D_MODEL) / 1024, 256, 0, stream>>>(x, xb);
    transpose_w_kernel<<<dim3(16, 16, 4), 256, 0, stream>>>(Wq, Wk, Wv, Wo, wt);

    // fused QKV projection; epilogue: z=0 Q(RoPE,*0.125), z=1 K(RoPE), z=2 V(transposed)
    gemm_kernel<4, 1><<<dim3(M_TOT / 128, D_MODEL / 128, 3), 256, 0, stream>>>(
        xb, wt, (void*)Qb, cosp, sinp);

    kmax_kernel<<<dim3(8, 32), 256, 0, stream>>>(Kb, Ks);

    // 512-thr blocks (8 waves), grid 512 = 2 blocks/CU, cooperative LDS staging
    attn_kernel<<<dim3(16, 32), 512, 0, stream>>>(Qb, Kb, Vtb, Ks, Zb);

    // out projection -> fp32 d_out
    gemm_kernel<2, 0><<<dim3(M_TOT / 64, D_MODEL / 128, 1), 256, 0, stream>>>(
        Zb, wt + (size_t)3 * D_MODEL * D_MODEL, d_out, nullptr, nullptr);
}

// Round 9
// 216.125 us; speedup vs baseline: 1.2438x; 1.0188x over previous
//
#include <hip/hip_runtime.h>

typedef __attribute__((ext_vector_type(4))) float f32x4;
typedef __attribute__((ext_vector_type(8))) short short8;
typedef __attribute__((ext_vector_type(8))) unsigned short u16x8;
typedef __attribute__((ext_vector_type(4))) unsigned short u16x4;
typedef __attribute__((ext_vector_type(2))) unsigned int u32x2;

#define D_MODEL 1024
#define NHEADS 16
#define T_SEQ 2048
#define M_TOT 4096   // B*T

__device__ __forceinline__ unsigned short f2bf(float f) {
    union { float f; unsigned int u; } v; v.f = f;
    return (unsigned short)((v.u + 0x7fffu + ((v.u >> 16) & 1u)) >> 16);
}
__device__ __forceinline__ float bf2f(unsigned short b) {
    union { unsigned int u; float f; } v; v.u = ((unsigned int)b) << 16;
    return v.f;
}
// packed f32x2 -> bf16x2 (low = src0, high = src1)
__device__ __forceinline__ unsigned int cvtpk_bf16(float lo, float hi) {
    unsigned int r;
    asm("v_cvt_pk_bf16_f32 %0, %1, %2" : "=v"(r) : "v"(lo), "v"(hi));
    return r;
}

// volatile asm load: issue point pinned (cannot be sunk/hoisted by the compiler)
#define GLD0(dst, addr) \
    asm volatile("global_load_dwordx4 %0, %1, off" : "=v"(dst) : "v"(addr) : "memory")
// wait all asm loads done, and fence the scheduler (guide rule #18)
#define WAITV0() do { asm volatile("s_waitcnt vmcnt(0)" ::: "memory"); \
                      __builtin_amdgcn_sched_barrier(0); } while (0)
// raw barrier: drain LDS only (NOT vmcnt -> in-flight prefetch survives the barrier)
#define LBAR() do { asm volatile("s_waitcnt lgkmcnt(0)" ::: "memory"); \
                    __builtin_amdgcn_s_barrier(); \
                    __builtin_amdgcn_sched_barrier(0); } while (0)

// ---------------- convert x fp32 -> bf16 ----------------
__global__ __launch_bounds__(256) void convert_x_kernel(const float* __restrict__ X,
                                                        unsigned short* __restrict__ Xb) {
    const int i = (blockIdx.x * 256 + threadIdx.x) * 4;
    const float4 v = *(const float4*)(X + i);
    u16x4 r;
    r.x = f2bf(v.x); r.y = f2bf(v.y); r.z = f2bf(v.z); r.w = f2bf(v.w);
    *(u16x4*)(Xb + i) = r;
}

// ---------------- 4x W [k][n] fp32 -> Wt [n][k] bf16, batched over z ----------------
__global__ __launch_bounds__(256) void transpose_w_kernel(const float* __restrict__ W0,
                                                          const float* __restrict__ W1,
                                                          const float* __restrict__ W2,
                                                          const float* __restrict__ W3,
                                                          unsigned short* __restrict__ Wt0) {
    __shared__ float tile[64][65];
    const int z = blockIdx.z;
    const float* W = (z == 0) ? W0 : (z == 1) ? W1 : (z == 2) ? W2 : W3;
    unsigned short* Wt = Wt0 + (size_t)z * D_MODEL * D_MODEL;
    const int n0 = blockIdx.x * 64, k0 = blockIdx.y * 64;
    for (int i = threadIdx.x; i < 4096; i += 256) {
        const int r = i >> 6, c = i & 63;
        tile[r][c] = W[(size_t)(k0 + r) * D_MODEL + n0 + c];
    }
    __syncthreads();
    for (int i = threadIdx.x; i < 4096; i += 256) {
        const int r = i >> 6, c = i & 63;  // r: n-local, c: k-local
        Wt[(size_t)(n0 + r) * D_MODEL + k0 + c] = f2bf(tile[c][r]);
    }
}

// ---------------- GEMM: C = A[M][1024] @ W, with Wt[n][k] pre-transposed ----------------
#define TN_G 128
#define BK_G 32
#define BKP_G 36

template<int MI, int OUTMODE>
__global__ __launch_bounds__(256) void gemm_kernel(
    const unsigned short* __restrict__ A,
    const unsigned short* __restrict__ Bt0,
    void* __restrict__ Cout0,
    const float* __restrict__ cosp,
    const float* __restrict__ sinp)
{
    constexpr int TMc = MI * 32;
    constexpr int NA = (TMc * 4) / 256;
    __shared__ unsigned short sA[TMc * BKP_G];
    __shared__ unsigned short sB[TN_G * BKP_G];

    const int tid = threadIdx.x;
    const int wid = tid >> 6;
    const int lane = tid & 63;
    const int quad = lane >> 4;
    const int l16 = lane & 15;
    const int wm = wid >> 1, wn = wid & 1;
    const int m0 = blockIdx.x * TMc, n0 = blockIdx.y * TN_G;
    const int z = blockIdx.z;
    const unsigned short* Bt = Bt0 + (size_t)z * D_MODEL * D_MODEL;

    f32x4 acc[MI][4] = {};

    for (int k0 = 0; k0 < D_MODEL; k0 += BK_G) {
        u16x8 av[NA], bv[2];
        #pragma unroll
        for (int i = 0; i < NA; ++i) {
            const int c = tid + i * 256, r = c >> 2, sg = (c & 3) * 8;
            av[i] = *(const u16x8*)(A + (size_t)(m0 + r) * D_MODEL + k0 + sg);
        }
        #pragma unroll
        for (int i = 0; i < 2; ++i) {
            const int c = tid + i * 256, r = c >> 2, sg = (c & 3) * 8;
            bv[i] = *(const u16x8*)(Bt + (size_t)(n0 + r) * D_MODEL + k0 + sg);
        }
        __syncthreads();
        #pragma unroll
        for (int i = 0; i < NA; ++i) {
            const int c = tid + i * 256, r = c >> 2, sg = (c & 3) * 8;
            *(u16x8*)&sA[r * BKP_G + sg] = av[i];
        }
        #pragma unroll
        for (int i = 0; i < 2; ++i) {
            const int c = tid + i * 256, r = c >> 2, sg = (c & 3) * 8;
            *(u16x8*)&sB[r * BKP_G + sg] = bv[i];
        }
        __syncthreads();

        short8 af[MI], bf[4];
        #pragma unroll
        for (int i = 0; i < MI; ++i)
            af[i] = *(const short8*)&sA[(wm * (MI * 16) + i * 16 + l16) * BKP_G + quad * 8];
        #pragma unroll
        for (int i = 0; i < 4; ++i)
            bf[i] = *(const short8*)&sB[(wn * 64 + i * 16 + l16) * BKP_G + quad * 8];
        #pragma unroll
        for (int mi = 0; mi < MI; ++mi)
            #pragma unroll
            for (int ni = 0; ni < 4; ++ni)
                acc[mi][ni] = __builtin_amdgcn_mfma_f32_16x16x32_bf16(af[mi], bf[ni], acc[mi][ni], 0, 0, 0);
    }

    if constexpr (OUTMODE == 0) {
        float* C = (float*)Cout0;
        #pragma unroll
        for (int mi = 0; mi < MI; ++mi) {
            const int mb = m0 + wm * (MI * 16) + mi * 16 + quad * 4;
            #pragma unroll
            for (int ni = 0; ni < 4; ++ni) {
                const int n = n0 + wn * 64 + ni * 16 + l16;
                #pragma unroll
                for (int r = 0; r < 4; ++r)
                    C[(size_t)(mb + r) * D_MODEL + n] = acc[mi][ni][r];
            }
        }
    } else {
        unsigned short* O = (unsigned short*)Cout0 + (size_t)z * M_TOT * D_MODEL;
        const int h = (n0 + wn * 64) >> 6;   // each wave's 64 cols = exactly one head
        if (z == 2) {
            // V: write transposed Vt[bh][d][t], packed u16x4 over 4 consecutive t
            #pragma unroll
            for (int mi = 0; mi < MI; ++mi) {
                const int mb = m0 + wm * (MI * 16) + mi * 16 + quad * 4;
                const int b = mb >> 11, t = mb & (T_SEQ - 1);
                #pragma unroll
                for (int ni = 0; ni < 4; ++ni) {
                    const int d = ni * 16 + l16;
                    u16x4 pk;
                    #pragma unroll
                    for (int r = 0; r < 4; ++r) pk[r] = f2bf(acc[mi][ni][r]);
                    *(u16x4*)(O + ((size_t)(b * NHEADS + h) * 64 + d) * T_SEQ + t) = pk;
                }
            }
        } else {
            const float qs = (z == 0) ? 0.125f : 1.0f;   // fold 1/sqrt(64) into Q (exact in bf16)
            #pragma unroll
            for (int mi = 0; mi < MI; ++mi) {
                #pragma unroll
                for (int r = 0; r < 4; ++r) {
                    const int m = m0 + wm * (MI * 16) + mi * 16 + quad * 4 + r;
                    const int b = m >> 11, t = m & (T_SEQ - 1);
                    const size_t rowoff = ((size_t)(b * NHEADS + h) * T_SEQ + t) * 64;
                    #pragma unroll
                    for (int ni = 0; ni < 2; ++ni) {
                        const int d = ni * 16 + l16;           // 0..31
                        const float c = cosp[t * 32 + d], s = sinp[t * 32 + d];
                        const float x1 = acc[mi][ni][r], x2 = acc[mi][ni + 2][r];
                        O[rowoff + d]      = f2bf((x1 * c - x2 * s) * qs);
                        O[rowoff + d + 32] = f2bf((x1 * s + x2 * c) * qs);
                    }
                }
            }
        }
    }
}

// ---------------- K row-norm segment maxes: Kseg[bh][8] = max ||k_row|| over 256-row segs ----------------
__global__ __launch_bounds__(256) void kmax_kernel(const unsigned short* __restrict__ Kg,
                                                   float* __restrict__ Kseg) {
    __shared__ float red[4];
    const int seg = blockIdx.x, bh = blockIdx.y;
    const unsigned short* Kp = Kg + ((size_t)bh * T_SEQ + seg * 256) * 64;
    const int row = threadIdx.x;   // one row per thread
    const u16x8* rp = (const u16x8*)(Kp + (size_t)row * 64);
    float s = 0.f;
    #pragma unroll
    for (int c = 0; c < 8; ++c) {
        const u16x8 v = rp[c];
        #pragma unroll
        for (int e = 0; e < 8; ++e) { const float f = bf2f(v[e]); s += f * f; }
    }
    #pragma unroll
    for (int off = 32; off >= 1; off >>= 1) s = fmaxf(s, __shfl_xor(s, off));
    if ((threadIdx.x & 63) == 0) red[threadIdx.x >> 6] = s;
    __syncthreads();
    if (threadIdx.x == 0)
        Kseg[bh * 8 + seg] = __builtin_sqrtf(fmaxf(fmaxf(red[0], red[1]), fmaxf(red[2], red[3])));
}

// ---------------- flash attention (causal): SINGLE-PASS, Cauchy-Schwarz max bound ----------------
// m_hat = ||q_row|| * max_j ||k_j|| >= max s (softmax shift-invariant -> exact math).
// p = exp2(s*log2e - m_hat*log2e) <= 1 structurally.
//
// R9 = R8 (cooperative LDS staging, VALIDATED: 103.5 -> 62.4us) + single-barrier
// double-buffered rounds:
//  - kv[2][4][4096] double buffer (64KB): per wave COMPUTE(t,buf) -> WAITV0 ->
//    WRITE(buf^1) -> LBAR. Ledger: COMPUTE(t-1) < WRITE(t) < LBAR_t in every wave's
//    program order => after LBAR_t nobody touches buf_{t-1} => writing it in round t
//    is race-free. ONE barrier/round (was 2) + staging decoupled from reads.
//  - P shrunk to LDPP=64 with XOR row-swizzle (idx ^= (l16&7)*8; 128B rows would be
//    16-way conflicted; XOR pattern verified balanced for b64 writes + b128 reads).
//    Total LDS = 65536 + 16384 = 81920 B exactly -> 2 blocks/CU at 160KB.
//  - lsum from raw p (drops 32 bit-ops/round; R0-proven semantics).
//  - s_setprio(1) around MFMA clusters.
#define LOG2E 1.44269504f

struct AttnSmem {
    union {
        unsigned short kv[2][4][4096];  // [buf][K0,V0,K1,V1][row*64 + swz-slot*8] = 65536 B
        float comb[4][64][34];          // 34816 B: half=1 partials (O 32 + lA + lB)
    } u;
    unsigned short P[8][16 * 64];       // per-wave P tile, XOR-swizzled rows = 16384 B
};                                      // total 81920 B

__global__ __launch_bounds__(512, 2) void attn_kernel(
    const unsigned short* __restrict__ Q,    // [bh][t][64] bf16, RoPE'd, pre-scaled 0.125
    const unsigned short* __restrict__ Kg,   // [bh][t][64] bf16, RoPE'd
    const unsigned short* __restrict__ Vt,   // [bh][d][t]  bf16 (transposed)
    const float* __restrict__ Kseg,          // [bh][8] segment maxes of ||k||
    unsigned short* __restrict__ Z)          // [m][h*64+d] bf16
{
    __shared__ AttnSmem sm;

    const int tid = threadIdx.x;
    const int wid = tid >> 6;        // 0..7
    const int w4 = wid & 3;          // row-slice within q-tile
    const int half = wid >> 2;       // 0: even j, 1: odd j
    const int lane = tid & 63;
    const int quad = lane >> 4;
    const int l16 = lane & 15;
    const int srow = tid >> 3;       // staging row 0..63
    const int sslot = tid & 7;       // staging 16B slot
    const int wslot = sslot ^ (srow & 7);          // swizzled slot
    const int sxK = (quad ^ (l16 & 7)) << 3;       // kv frag-read swizzled elem offset
    const int ph8 = (l16 & 7) << 3;                // P row XOR (u16 units)

    // XCD-locality remap (bijective): flat%8 selects XCD; each XCD owns 4 whole bh.
    const int flat = blockIdx.x + 16 * blockIdx.y;     // 0..511
    const int xcd = flat & 7, idx = flat >> 3;         // idx 0..63
    const int bh = xcd * 4 + (idx & 3);                // 0..31
    const int x = idx >> 2;                            // 0..15

    const int qA = x, qB = 31 - x;       // paired q-tiles: 33 tiles/block, constant
    const int jend = 31 - x;             // kv tiles 0..jend cover both

    const unsigned short* Qp = Q + (size_t)bh * T_SEQ * 64;
    const unsigned short* Kp = Kg + (size_t)bh * T_SEQ * 64;
    const unsigned short* Vp = Vt + (size_t)bh * 64 * T_SEQ;

    // Q frags (B-operand in swapped QK): row = qt*64 + w4*16 + l16, k = ks*32 + quad*8
    short8 aqA[2], aqB[2];
    {
        const unsigned short* qr = Qp + (size_t)(qA * 64 + w4 * 16 + l16) * 64 + quad * 8;
        aqA[0] = *(const short8*)(qr);
        aqA[1] = *(const short8*)(qr + 32);
        qr = Qp + (size_t)(qB * 64 + w4 * 16 + l16) * 64 + quad * 8;
        aqB[0] = *(const short8*)(qr);
        aqB[1] = *(const short8*)(qr + 32);
    }

    // max bound: per-lane scalar for q-row l16 (swapped layout: lane = q-row)
    float kmx = 0.f;
    #pragma unroll
    for (int i = 0; i < 8; ++i) kmx = fmaxf(kmx, Kseg[bh * 8 + i]);

    float mQA, mQB;
    {
        float nqA = 0.f, nqB = 0.f;
        #pragma unroll
        for (int i = 0; i < 2; ++i)
            #pragma unroll
            for (int e = 0; e < 8; ++e) {
                const float fa = bf2f((unsigned short)aqA[i][e]);
                const float fb = bf2f((unsigned short)aqB[i][e]);
                nqA += fa * fa; nqB += fb * fb;
            }
        nqA += __shfl_xor(nqA, 16); nqA += __shfl_xor(nqA, 32);
        nqB += __shfl_xor(nqB, 16); nqB += __shfl_xor(nqB, 32);
        mQA = __builtin_sqrtf(nqA) * kmx * LOG2E;
        mQB = __builtin_sqrtf(nqB) * kmx * LOG2E;
    }

    auto tile_pack = [&](f32x4 (&s)[4], float mQ, float& lsum, bool msk,
                         unsigned short* Pw) {
        if (msk) {
            #pragma unroll
            for (int nt = 0; nt < 4; ++nt)
                #pragma unroll
                for (int r = 0; r < 4; ++r)
                    if (nt * 16 + quad * 4 + r > w4 * 16 + l16) s[nt][r] = -1e30f;
        }
        #pragma unroll
        for (int nt = 0; nt < 4; ++nt) {
            const float p0 = __builtin_exp2f(s[nt][0] * LOG2E - mQ);
            const float p1 = __builtin_exp2f(s[nt][1] * LOG2E - mQ);
            const float p2 = __builtin_exp2f(s[nt][2] * LOG2E - mQ);
            const float p3 = __builtin_exp2f(s[nt][3] * LOG2E - mQ);
            lsum += (p0 + p1) + (p2 + p3);
            const unsigned int w0 = cvtpk_bf16(p0, p1);
            const unsigned int w1 = cvtpk_bf16(p2, p3);
            *(u32x2*)&Pw[l16 * 64 + ((nt * 16 + quad * 4) ^ ph8)] = (u32x2){w0, w1};
        }
    };

    f32x4 oA[4] = {}, oB[4] = {};
    float lA = 0.f, lB = 0.f;
    unsigned short* Pw = &sm.P[wid][0];

    short8 stg[4];
    auto ISSUE = [&](int t) {   // 4 contiguous 16B loads per thread (pinned issue)
        const int j0 = 2 * t, j1 = j0 + 1;
        GLD0(stg[0], Kp + (size_t)j0 * 4096 + tid * 8);
        GLD0(stg[1], Vp + (size_t)srow * 2048 + j0 * 64 + sslot * 8);
        GLD0(stg[2], Kp + (size_t)j1 * 4096 + tid * 8);
        GLD0(stg[3], Vp + (size_t)srow * 2048 + j1 * 64 + sslot * 8);
    };
    auto WRITE = [&](int b) {   // swizzled LDS store of the staged 64B
        const int dst = srow * 64 + (wslot << 3);
        *(short8*)&sm.u.kv[b][0][dst] = stg[0];
        *(short8*)&sm.u.kv[b][1][dst] = stg[1];
        *(short8*)&sm.u.kv[b][2][dst] = stg[2];
        *(short8*)&sm.u.kv[b][3][dst] = stg[3];
    };

    auto COMPUTE = [&](int j, int b) {
        if (j > jend) return;            // last round: odd half may be inactive
        const bool doA = (j <= x);
        const unsigned short* sKb = &sm.u.kv[b][half * 2][0];
        const unsigned short* sVb = &sm.u.kv[b][half * 2 + 1][0];
        f32x4 sA[4] = {}, sB[4] = {};
        __builtin_amdgcn_s_setprio(1);
        #pragma unroll
        for (int nt = 0; nt < 4; ++nt) {
            const int rb = (nt * 16 + l16) * 64;
            const short8 k0 = *(const short8*)&sKb[rb + sxK];
            const short8 k1 = *(const short8*)&sKb[rb + (sxK ^ 32)];
            if (doA) {
                sA[nt] = __builtin_amdgcn_mfma_f32_16x16x32_bf16(k0, aqA[0], sA[nt], 0, 0, 0);
                sA[nt] = __builtin_amdgcn_mfma_f32_16x16x32_bf16(k1, aqA[1], sA[nt], 0, 0, 0);
            }
            sB[nt] = __builtin_amdgcn_mfma_f32_16x16x32_bf16(k0, aqB[0], sB[nt], 0, 0, 0);
            sB[nt] = __builtin_amdgcn_mfma_f32_16x16x32_bf16(k1, aqB[1], sB[nt], 0, 0, 0);
        }
        __builtin_amdgcn_s_setprio(0);
        short8 pfA0 = {}, pfA1 = {};
        if (doA) {
            tile_pack(sA, mQA, lA, j == x, Pw);
            asm volatile("s_waitcnt lgkmcnt(0)" ::: "memory");
            pfA0 = *(const short8*)&Pw[l16 * 64 + ((quad * 8) ^ ph8)];
            pfA1 = *(const short8*)&Pw[l16 * 64 + ((32 + quad * 8) ^ ph8)];
        }
        tile_pack(sB, mQB, lB, j == jend, Pw);
        asm volatile("s_waitcnt lgkmcnt(0)" ::: "memory");
        const short8 pfB0 = *(const short8*)&Pw[l16 * 64 + ((quad * 8) ^ ph8)];
        const short8 pfB1 = *(const short8*)&Pw[l16 * 64 + ((32 + quad * 8) ^ ph8)];
        __builtin_amdgcn_s_setprio(1);
        #pragma unroll
        for (int dt = 0; dt < 4; ++dt) {
            const int rb = (dt * 16 + l16) * 64;
            const short8 v0 = *(const short8*)&sVb[rb + sxK];
            const short8 v1 = *(const short8*)&sVb[rb + (sxK ^ 32)];
            if (doA) {
                oA[dt] = __builtin_amdgcn_mfma_f32_16x16x32_bf16(pfA0, v0, oA[dt], 0, 0, 0);
                oA[dt] = __builtin_amdgcn_mfma_f32_16x16x32_bf16(pfA1, v1, oA[dt], 0, 0, 0);
            }
            oB[dt] = __builtin_amdgcn_mfma_f32_16x16x32_bf16(pfB0, v0, oB[dt], 0, 0, 0);
            oB[dt] = __builtin_amdgcn_mfma_f32_16x16x32_bf16(pfB1, v1, oB[dt], 0, 0, 0);
        }
        __builtin_amdgcn_s_setprio(0);
    };

    // ---- single-barrier double-buffered pipeline ----
    const int nr = (jend >> 1) + 1;      // block-uniform round count
    ISSUE(0);
    WAITV0();
    WRITE(0);
    LBAR();
    for (int t = 0; t < nr; ++t) {
        const bool more = (t + 1 < nr);
        if (more) ISSUE(t + 1);          // loads fly during COMPUTE
        COMPUTE(2 * t + half, t & 1);
        if (more) {
            WAITV0();                    // staged data arrived
            WRITE((t + 1) & 1);          // other buffer: nobody reads it (ledger)
        }
        LBAR();                          // one barrier per round
    }

    // per-lane row totals (row = l16): reduce across quads
    lA += __shfl_xor(lA, 16); lA += __shfl_xor(lA, 32);
    lB += __shfl_xor(lB, 16); lB += __shfl_xor(lB, 32);

    // combine halves: fixed m_hat => partials add directly (no rescale).
    __syncthreads();
    if (half) {
        float* cb = &sm.u.comb[w4][lane][0];
        #pragma unroll
        for (int dt = 0; dt < 4; ++dt)
            #pragma unroll
            for (int r = 0; r < 4; ++r) {
                cb[dt * 4 + r]      = oA[dt][r];
                cb[16 + dt * 4 + r] = oB[dt][r];
            }
        cb[32] = lA; cb[33] = lB;
    }
    __syncthreads();
    if (half) return;

    {
        const float* cb = &sm.u.comb[w4][lane][0];
        #pragma unroll
        for (int dt = 0; dt < 4; ++dt)
            #pragma unroll
            for (int r = 0; r < 4; ++r) {
                oA[dt][r] += cb[dt * 4 + r];
                oB[dt][r] += cb[16 + dt * 4 + r];
            }
        lA += cb[32]; lB += cb[33];
    }

    // invert per-lane (row l16), then gather to C-rows (quad*4+r)
    const float iA = 1.f / lA, iB = 1.f / lB;
    float irA[4], irB[4];
    #pragma unroll
    for (int r = 0; r < 4; ++r) {
        const int src = (lane & 48) | (quad * 4 + r);
        irA[r] = __shfl(iA, src);
        irB[r] = __shfl(iB, src);
    }

    // epilogue: normalize and write
    const int h = bh & 15, b = bh >> 4;
    #pragma unroll
    for (int dt = 0; dt < 4; ++dt)
        #pragma unroll
        for (int r = 0; r < 4; ++r) {
            const int rowA = qA * 64 + w4 * 16 + quad * 4 + r;
            const int rowB = qB * 64 + w4 * 16 + quad * 4 + r;
            const int col = h * 64 + dt * 16 + l16;
            Z[((size_t)b * T_SEQ + rowA) * D_MODEL + col] = f2bf(oA[dt][r] * irA[r]);
            Z[((size_t)b * T_SEQ + rowB) * D_MODEL + col] = f2bf(oB[dt][r] * irB[r]);
        }
}

// ---------------- launcher ----------------
extern "C" void kernel_launch(void* const* d_in, const int* in_sizes, int n_in,
                              void* d_out, int out_size, void* d_ws, size_t ws_size,
                              hipStream_t stream) {
    const float* x    = (const float*)d_in[0];
    const float* cosp = (const float*)d_in[1];
    const float* sinp = (const float*)d_in[2];
    const float* Wq   = (const float*)d_in[3];
    const float* Wk   = (const float*)d_in[4];
    const float* Wv   = (const float*)d_in[5];
    const float* Wo   = (const float*)d_in[6];

    char* w = (char*)d_ws;
    unsigned short* xb  = (unsigned short*)w; w += (size_t)M_TOT * D_MODEL * 2;    // 8 MB
    unsigned short* wt  = (unsigned short*)w; w += (size_t)4 * D_MODEL * D_MODEL * 2; // 8 MB (q,k,v,o)
    unsigned short* Qb  = (unsigned short*)w; w += (size_t)M_TOT * D_MODEL * 2;    // 8 MB
    unsigned short* Kb  = (unsigned short*)w; w += (size_t)M_TOT * D_MODEL * 2;
    unsigned short* Vtb = (unsigned short*)w; w += (size_t)M_TOT * D_MODEL * 2;    // [bh][d][t]
    unsigned short* Zb  = (unsigned short*)w; w += (size_t)M_TOT * D_MODEL * 2;
    float*          Ks  = (float*)w;          w += 32 * 8 * sizeof(float);         // Kseg[bh][8]

    convert_x_kernel<<<(M_TOT * D_MODEL) / 1024, 256, 0, stream>>>(x, xb);
    transpose_w_kernel<<<dim3(16, 16, 4), 256, 0, stream>>>(Wq, Wk, Wv, Wo, wt);

    // fused QKV projection; epilogue: z=0 Q(RoPE,*0.125), z=1 K(RoPE), z=2 V(transposed)
    gemm_kernel<4, 1><<<dim3(M_TOT / 128, D_MODEL / 128, 3), 256, 0, stream>>>(
        xb, wt, (void*)Qb, cosp, sinp);

    kmax_kernel<<<dim3(8, 32), 256, 0, stream>>>(Kb, Ks);

    // 512-thr blocks (8 waves), grid 512 = 2 blocks/CU, double-buffered staging
    attn_kernel<<<dim3(16, 32), 512, 0, stream>>>(Qb, Kb, Vtb, Ks, Zb);

    // out projection -> fp32 d_out
    gemm_kernel<2, 0><<<dim3(M_TOT / 64, D_MODEL / 128, 1), 256, 0, stream>>>(
        Zb, wt + (size_t)3 * D_MODEL * D_MODEL, d_out, nullptr, nullptr);
}

// Round 10
// 212.199 us; speedup vs baseline: 1.2668x; 1.0185x over previous
//
#include <hip/hip_runtime.h>

typedef __attribute__((ext_vector_type(4))) float f32x4;
typedef __attribute__((ext_vector_type(8))) short short8;
typedef __attribute__((ext_vector_type(8))) unsigned short u16x8;
typedef __attribute__((ext_vector_type(4))) unsigned short u16x4;
typedef __attribute__((ext_vector_type(2))) unsigned int u32x2;

#define D_MODEL 1024
#define NHEADS 16
#define T_SEQ 2048
#define M_TOT 4096   // B*T

__device__ __forceinline__ unsigned short f2bf(float f) {
    union { float f; unsigned int u; } v; v.f = f;
    return (unsigned short)((v.u + 0x7fffu + ((v.u >> 16) & 1u)) >> 16);
}
__device__ __forceinline__ float bf2f(unsigned short b) {
    union { unsigned int u; float f; } v; v.u = ((unsigned int)b) << 16;
    return v.f;
}
// packed f32x2 -> bf16x2 (low = src0, high = src1)
__device__ __forceinline__ unsigned int cvtpk_bf16(float lo, float hi) {
    unsigned int r;
    asm("v_cvt_pk_bf16_f32 %0, %1, %2" : "=v"(r) : "v"(lo), "v"(hi));
    return r;
}

// volatile asm load: issue point pinned (cannot be sunk/hoisted by the compiler)
#define GLD0(dst, addr) \
    asm volatile("global_load_dwordx4 %0, %1, off" : "=v"(dst) : "v"(addr) : "memory")
// wait all asm loads done, and fence the scheduler (guide rule #18)
#define WAITV0() do { asm volatile("s_waitcnt vmcnt(0)" ::: "memory"); \
                      __builtin_amdgcn_sched_barrier(0); } while (0)
// raw barrier: drain LDS only (NOT vmcnt -> in-flight prefetch survives the barrier)
#define LBAR() do { asm volatile("s_waitcnt lgkmcnt(0)" ::: "memory"); \
                    __builtin_amdgcn_s_barrier(); \
                    __builtin_amdgcn_sched_barrier(0); } while (0)

// async global -> LDS, 16B per lane, LDS dest = wave-uniform base + lane*16
#define GLDS16(gp, lp) \
    __builtin_amdgcn_global_load_lds((const __attribute__((address_space(1))) void*)(gp), \
                                     (__attribute__((address_space(3))) void*)(lp), 16, 0, 0)

// ---------------- prep: convert x fp32->bf16  +  4x W transpose->bf16 (one launch) ----------------
__global__ __launch_bounds__(256) void prep_kernel(const float* __restrict__ X,
                                                   unsigned short* __restrict__ Xb,
                                                   const float* __restrict__ W0,
                                                   const float* __restrict__ W1,
                                                   const float* __restrict__ W2,
                                                   const float* __restrict__ W3,
                                                   unsigned short* __restrict__ Wt0) {
    __shared__ float tile[64][65];
    const int z = blockIdx.z;
    if (z >= 4) {
        // convert: 16 z-slices x 256 blocks x 256 thr x 4 floats = 4096*1024
        const int blk = (z - 4) * 256 + blockIdx.y * 16 + blockIdx.x;
        const int i = (blk * 256 + threadIdx.x) * 4;
        const float4 v = *(const float4*)(X + i);
        u16x4 r;
        r.x = f2bf(v.x); r.y = f2bf(v.y); r.z = f2bf(v.z); r.w = f2bf(v.w);
        *(u16x4*)(Xb + i) = r;
        return;
    }
    const float* W = (z == 0) ? W0 : (z == 1) ? W1 : (z == 2) ? W2 : W3;
    unsigned short* Wt = Wt0 + (size_t)z * D_MODEL * D_MODEL;
    const int n0 = blockIdx.x * 64, k0 = blockIdx.y * 64;
    for (int i = threadIdx.x; i < 4096; i += 256) {
        const int r = i >> 6, c = i & 63;
        tile[r][c] = W[(size_t)(k0 + r) * D_MODEL + n0 + c];
    }
    __syncthreads();
    for (int i = threadIdx.x; i < 4096; i += 256) {
        const int r = i >> 6, c = i & 63;  // r: n-local, c: k-local
        Wt[(size_t)(n0 + r) * D_MODEL + k0 + c] = f2bf(tile[c][r]);
    }
}

// ---------------- GEMM: C = A[M][1024] @ W, Wt[n][k] pre-transposed ----------------
// R10: global_load_lds staging (m97 structure; m151 A/B: reg-staged 646 -> glds 874 TF).
// LDS tiles LINEAR [rows][32] (builtin writes base + lane*16; no padding possible).
// Per K-step: chunks of 16 rows (1KB); (TMc+128)/16 chunks round-robin over 4 waves.
// kmax FUSED into z==1 epilogue: wave's 64 cols = one head; norm from fp32 acc
// (RoPE is a rotation -> norm-preserving; bf16-rounding margin bounds p <= ~1.01,
// safe since softmax is shift-invariant). Deterministic slots Ks[bh][32], all
// written every launch (no stale-workspace hazard).
#define TN_G 128
#define BK_G 32

template<int MI, int OUTMODE>
__global__ __launch_bounds__(256) void gemm_kernel(
    const unsigned short* __restrict__ A,
    const unsigned short* __restrict__ Bt0,
    void* __restrict__ Cout0,
    const float* __restrict__ cosp,
    const float* __restrict__ sinp,
    float* __restrict__ Kmax)
{
    constexpr int TMc = MI * 32;
    constexpr int NCHA = TMc / 16;          // A chunks (1KB each)
    __shared__ unsigned short sA[TMc * 32];
    __shared__ unsigned short sB[TN_G * 32];

    const int tid = threadIdx.x;
    const int wid = tid >> 6;
    const int lane = tid & 63;
    const int quad = lane >> 4;
    const int l16 = lane & 15;
    const int wm = wid >> 1, wn = wid & 1;
    const int m0 = blockIdx.x * TMc, n0 = blockIdx.y * TN_G;
    const int z = blockIdx.z;
    const unsigned short* Bt = Bt0 + (size_t)z * D_MODEL * D_MODEL;
    const int srowL = lane >> 2;            // staging row within chunk
    const int scolL = (lane & 3) * 8;       // staging u16 col

    f32x4 acc[MI][4] = {};

    for (int k0 = 0; k0 < D_MODEL; k0 += BK_G) {
        #pragma unroll
        for (int ch = wid; ch < NCHA + 8; ch += 4) {
            if (ch < NCHA) {
                GLDS16(A + (size_t)(m0 + ch * 16 + srowL) * D_MODEL + k0 + scolL,
                       &sA[ch * 512]);
            } else {
                GLDS16(Bt + (size_t)(n0 + (ch - NCHA) * 16 + srowL) * D_MODEL + k0 + scolL,
                       &sB[(ch - NCHA) * 512]);
            }
        }
        __syncthreads();   // drains vmcnt -> staged data in LDS

        short8 af[MI], bf[4];
        #pragma unroll
        for (int i = 0; i < MI; ++i)
            af[i] = *(const short8*)&sA[(wm * (MI * 16) + i * 16 + l16) * 32 + quad * 8];
        #pragma unroll
        for (int i = 0; i < 4; ++i)
            bf[i] = *(const short8*)&sB[(wn * 64 + i * 16 + l16) * 32 + quad * 8];
        #pragma unroll
        for (int mi = 0; mi < MI; ++mi)
            #pragma unroll
            for (int ni = 0; ni < 4; ++ni)
                acc[mi][ni] = __builtin_amdgcn_mfma_f32_16x16x32_bf16(af[mi], bf[ni], acc[mi][ni], 0, 0, 0);
        __syncthreads();   // frag reads done before next stage overwrites
    }

    if constexpr (OUTMODE == 0) {
        float* C = (float*)Cout0;
        #pragma unroll
        for (int mi = 0; mi < MI; ++mi) {
            const int mb = m0 + wm * (MI * 16) + mi * 16 + quad * 4;
            #pragma unroll
            for (int ni = 0; ni < 4; ++ni) {
                const int n = n0 + wn * 64 + ni * 16 + l16;
                #pragma unroll
                for (int r = 0; r < 4; ++r)
                    C[(size_t)(mb + r) * D_MODEL + n] = acc[mi][ni][r];
            }
        }
    } else {
        unsigned short* O = (unsigned short*)Cout0 + (size_t)z * M_TOT * D_MODEL;
        const int h = (n0 + wn * 64) >> 6;   // each wave's 64 cols = exactly one head
        if (z == 2) {
            // V: write transposed Vt[bh][d][t], packed u16x4 over 4 consecutive t
            #pragma unroll
            for (int mi = 0; mi < MI; ++mi) {
                const int mb = m0 + wm * (MI * 16) + mi * 16 + quad * 4;
                const int b = mb >> 11, t = mb & (T_SEQ - 1);
                #pragma unroll
                for (int ni = 0; ni < 4; ++ni) {
                    const int d = ni * 16 + l16;
                    u16x4 pk;
                    #pragma unroll
                    for (int r = 0; r < 4; ++r) pk[r] = f2bf(acc[mi][ni][r]);
                    *(u16x4*)(O + ((size_t)(b * NHEADS + h) * 64 + d) * T_SEQ + t) = pk;
                }
            }
        } else {
            if (z == 1) {
                // fused kmax: max ||k_row|| over this wave's 64 rows (one head)
                float mx = 0.f;
                #pragma unroll
                for (int mi = 0; mi < MI; ++mi)
                    #pragma unroll
                    for (int r = 0; r < 4; ++r) {
                        float s = 0.f;
                        #pragma unroll
                        for (int ni = 0; ni < 4; ++ni) s += acc[mi][ni][r] * acc[mi][ni][r];
                        s += __shfl_xor(s, 1); s += __shfl_xor(s, 2);
                        s += __shfl_xor(s, 4); s += __shfl_xor(s, 8);
                        mx = fmaxf(mx, s);
                    }
                mx = fmaxf(mx, __shfl_xor(mx, 16));
                mx = fmaxf(mx, __shfl_xor(mx, 32));
                if (lane == 0) {
                    const int b = m0 >> 11;
                    const int slot = ((m0 >> 7) & 15) * 2 + wm;
                    Kmax[(size_t)(b * NHEADS + h) * 32 + slot] = __builtin_sqrtf(mx);
                }
            }
            const float qs = (z == 0) ? 0.125f : 1.0f;   // fold 1/sqrt(64) into Q (exact in bf16)
            #pragma unroll
            for (int mi = 0; mi < MI; ++mi) {
                #pragma unroll
                for (int r = 0; r < 4; ++r) {
                    const int m = m0 + wm * (MI * 16) + mi * 16 + quad * 4 + r;
                    const int b = m >> 11, t = m & (T_SEQ - 1);
                    const size_t rowoff = ((size_t)(b * NHEADS + h) * T_SEQ + t) * 64;
                    #pragma unroll
                    for (int ni = 0; ni < 2; ++ni) {
                        const int d = ni * 16 + l16;           // 0..31
                        const float c = cosp[t * 32 + d], s = sinp[t * 32 + d];
                        const float x1 = acc[mi][ni][r], x2 = acc[mi][ni + 2][r];
                        O[rowoff + d]      = f2bf((x1 * c - x2 * s) * qs);
                        O[rowoff + d + 32] = f2bf((x1 * s + x2 * c) * qs);
                    }
                }
            }
        }
    }
}

// ---------------- flash attention (causal): SINGLE-PASS, Cauchy-Schwarz max bound ----------------
// m_hat = ||q_row|| * max_j ||k_j|| >= max s (softmax shift-invariant -> exact math).
// p = exp2(s*log2e - m_hat*log2e) <= ~1 structurally.
// R9 structure (validated 57.5us): cooperative LDS staging, kv double buffer,
// one barrier/round, XOR-swizzled P, setprio around MFMA. Only change: Kseg is
// now [bh][32] (written by the fused gemm epilogue).
#define LOG2E 1.44269504f

struct AttnSmem {
    union {
        unsigned short kv[2][4][4096];  // [buf][K0,V0,K1,V1][row*64 + swz-slot*8] = 65536 B
        float comb[4][64][34];          // 34816 B: half=1 partials (O 32 + lA + lB)
    } u;
    unsigned short P[8][16 * 64];       // per-wave P tile, XOR-swizzled rows = 16384 B
};                                      // total 81920 B

__global__ __launch_bounds__(512, 2) void attn_kernel(
    const unsigned short* __restrict__ Q,    // [bh][t][64] bf16, RoPE'd, pre-scaled 0.125
    const unsigned short* __restrict__ Kg,   // [bh][t][64] bf16, RoPE'd
    const unsigned short* __restrict__ Vt,   // [bh][d][t]  bf16 (transposed)
    const float* __restrict__ Kseg,          // [bh][32] segment maxes of ||k||
    unsigned short* __restrict__ Z)          // [m][h*64+d] bf16
{
    __shared__ AttnSmem sm;

    const int tid = threadIdx.x;
    const int wid = tid >> 6;        // 0..7
    const int w4 = wid & 3;          // row-slice within q-tile
    const int half = wid >> 2;       // 0: even j, 1: odd j
    const int lane = tid & 63;
    const int quad = lane >> 4;
    const int l16 = lane & 15;
    const int srow = tid >> 3;       // staging row 0..63
    const int sslot = tid & 7;       // staging 16B slot
    const int wslot = sslot ^ (srow & 7);          // swizzled slot
    const int sxK = (quad ^ (l16 & 7)) << 3;       // kv frag-read swizzled elem offset
    const int ph8 = (l16 & 7) << 3;                // P row XOR (u16 units)

    // XCD-locality remap (bijective): flat%8 selects XCD; each XCD owns 4 whole bh.
    const int flat = blockIdx.x + 16 * blockIdx.y;     // 0..511
    const int xcd = flat & 7, idx = flat >> 3;         // idx 0..63
    const int bh = xcd * 4 + (idx & 3);                // 0..31
    const int x = idx >> 2;                            // 0..15

    const int qA = x, qB = 31 - x;       // paired q-tiles: 33 tiles/block, constant
    const int jend = 31 - x;             // kv tiles 0..jend cover both

    const unsigned short* Qp = Q + (size_t)bh * T_SEQ * 64;
    const unsigned short* Kp = Kg + (size_t)bh * T_SEQ * 64;
    const unsigned short* Vp = Vt + (size_t)bh * 64 * T_SEQ;

    // Q frags (B-operand in swapped QK): row = qt*64 + w4*16 + l16, k = ks*32 + quad*8
    short8 aqA[2], aqB[2];
    {
        const unsigned short* qr = Qp + (size_t)(qA * 64 + w4 * 16 + l16) * 64 + quad * 8;
        aqA[0] = *(const short8*)(qr);
        aqA[1] = *(const short8*)(qr + 32);
        qr = Qp + (size_t)(qB * 64 + w4 * 16 + l16) * 64 + quad * 8;
        aqB[0] = *(const short8*)(qr);
        aqB[1] = *(const short8*)(qr + 32);
    }

    // max bound: per-lane scalar for q-row l16 (swapped layout: lane = q-row)
    float kmx = 0.f;
    #pragma unroll
    for (int i = 0; i < 32; ++i) kmx = fmaxf(kmx, Kseg[bh * 32 + i]);

    float mQA, mQB;
    {
        float nqA = 0.f, nqB = 0.f;
        #pragma unroll
        for (int i = 0; i < 2; ++i)
            #pragma unroll
            for (int e = 0; e < 8; ++e) {
                const float fa = bf2f((unsigned short)aqA[i][e]);
                const float fb = bf2f((unsigned short)aqB[i][e]);
                nqA += fa * fa; nqB += fb * fb;
            }
        nqA += __shfl_xor(nqA, 16); nqA += __shfl_xor(nqA, 32);
        nqB += __shfl_xor(nqB, 16); nqB += __shfl_xor(nqB, 32);
        mQA = __builtin_sqrtf(nqA) * kmx * LOG2E;
        mQB = __builtin_sqrtf(nqB) * kmx * LOG2E;
    }

    auto tile_pack = [&](f32x4 (&s)[4], float mQ, float& lsum, bool msk,
                         unsigned short* Pw) {
        if (msk) {
            #pragma unroll
            for (int nt = 0; nt < 4; ++nt)
                #pragma unroll
                for (int r = 0; r < 4; ++r)
                    if (nt * 16 + quad * 4 + r > w4 * 16 + l16) s[nt][r] = -1e30f;
        }
        #pragma unroll
        for (int nt = 0; nt < 4; ++nt) {
            const float p0 = __builtin_exp2f(s[nt][0] * LOG2E - mQ);
            const float p1 = __builtin_exp2f(s[nt][1] * LOG2E - mQ);
            const float p2 = __builtin_exp2f(s[nt][2] * LOG2E - mQ);
            const float p3 = __builtin_exp2f(s[nt][3] * LOG2E - mQ);
            lsum += (p0 + p1) + (p2 + p3);
            const unsigned int w0 = cvtpk_bf16(p0, p1);
            const unsigned int w1 = cvtpk_bf16(p2, p3);
            *(u32x2*)&Pw[l16 * 64 + ((nt * 16 + quad * 4) ^ ph8)] = (u32x2){w0, w1};
        }
    };

    f32x4 oA[4] = {}, oB[4] = {};
    float lA = 0.f, lB = 0.f;
    unsigned short* Pw = &sm.P[wid][0];

    short8 stg[4];
    auto ISSUE = [&](int t) {   // 4 contiguous 16B loads per thread (pinned issue)
        const int j0 = 2 * t, j1 = j0 + 1;
        GLD0(stg[0], Kp + (size_t)j0 * 4096 + tid * 8);
        GLD0(stg[1], Vp + (size_t)srow * 2048 + j0 * 64 + sslot * 8);
        GLD0(stg[2], Kp + (size_t)j1 * 4096 + tid * 8);
        GLD0(stg[3], Vp + (size_t)srow * 2048 + j1 * 64 + sslot * 8);
    };
    auto WRITE = [&](int b) {   // swizzled LDS store of the staged 64B
        const int dst = srow * 64 + (wslot << 3);
        *(short8*)&sm.u.kv[b][0][dst] = stg[0];
        *(short8*)&sm.u.kv[b][1][dst] = stg[1];
        *(short8*)&sm.u.kv[b][2][dst] = stg[2];
        *(short8*)&sm.u.kv[b][3][dst] = stg[3];
    };

    auto COMPUTE = [&](int j, int b) {
        if (j > jend) return;            // last round: odd half may be inactive
        const bool doA = (j <= x);
        const unsigned short* sKb = &sm.u.kv[b][half * 2][0];
        const unsigned short* sVb = &sm.u.kv[b][half * 2 + 1][0];
        f32x4 sA[4] = {}, sB[4] = {};
        __builtin_amdgcn_s_setprio(1);
        #pragma unroll
        for (int nt = 0; nt < 4; ++nt) {
            const int rb = (nt * 16 + l16) * 64;
            const short8 k0 = *(const short8*)&sKb[rb + sxK];
            const short8 k1 = *(const short8*)&sKb[rb + (sxK ^ 32)];
            if (doA) {
                sA[nt] = __builtin_amdgcn_mfma_f32_16x16x32_bf16(k0, aqA[0], sA[nt], 0, 0, 0);
                sA[nt] = __builtin_amdgcn_mfma_f32_16x16x32_bf16(k1, aqA[1], sA[nt], 0, 0, 0);
            }
            sB[nt] = __builtin_amdgcn_mfma_f32_16x16x32_bf16(k0, aqB[0], sB[nt], 0, 0, 0);
            sB[nt] = __builtin_amdgcn_mfma_f32_16x16x32_bf16(k1, aqB[1], sB[nt], 0, 0, 0);
        }
        __builtin_amdgcn_s_setprio(0);
        short8 pfA0 = {}, pfA1 = {};
        if (doA) {
            tile_pack(sA, mQA, lA, j == x, Pw);
            asm volatile("s_waitcnt lgkmcnt(0)" ::: "memory");
            pfA0 = *(const short8*)&Pw[l16 * 64 + ((quad * 8) ^ ph8)];
            pfA1 = *(const short8*)&Pw[l16 * 64 + ((32 + quad * 8) ^ ph8)];
        }
        tile_pack(sB, mQB, lB, j == jend, Pw);
        asm volatile("s_waitcnt lgkmcnt(0)" ::: "memory");
        const short8 pfB0 = *(const short8*)&Pw[l16 * 64 + ((quad * 8) ^ ph8)];
        const short8 pfB1 = *(const short8*)&Pw[l16 * 64 + ((32 + quad * 8) ^ ph8)];
        __builtin_amdgcn_s_setprio(1);
        #pragma unroll
        for (int dt = 0; dt < 4; ++dt) {
            const int rb = (dt * 16 + l16) * 64;
            const short8 v0 = *(const short8*)&sVb[rb + sxK];
            const short8 v1 = *(const short8*)&sVb[rb + (sxK ^ 32)];
            if (doA) {
                oA[dt] = __builtin_amdgcn_mfma_f32_16x16x32_bf16(pfA0, v0, oA[dt], 0, 0, 0);
                oA[dt] = __builtin_amdgcn_mfma_f32_16x16x32_bf16(pfA1, v1, oA[dt], 0, 0, 0);
            }
            oB[dt] = __builtin_amdgcn_mfma_f32_16x16x32_bf16(pfB0, v0, oB[dt], 0, 0, 0);
            oB[dt] = __builtin_amdgcn_mfma_f32_16x16x32_bf16(pfB1, v1, oB[dt], 0, 0, 0);
        }
        __builtin_amdgcn_s_setprio(0);
    };

    // ---- single-barrier double-buffered pipeline ----
    const int nr = (jend >> 1) + 1;      // block-uniform round count
    ISSUE(0);
    WAITV0();
    WRITE(0);
    LBAR();
    for (int t = 0; t < nr; ++t) {
        const bool more = (t + 1 < nr);
        if (more) ISSUE(t + 1);          // loads fly during COMPUTE
        COMPUTE(2 * t + half, t & 1);
        if (more) {
            WAITV0();                    // staged data arrived
            WRITE((t + 1) & 1);          // other buffer: nobody reads it (ledger)
        }
        LBAR();                          // one barrier per round
    }

    // per-lane row totals (row = l16): reduce across quads
    lA += __shfl_xor(lA, 16); lA += __shfl_xor(lA, 32);
    lB += __shfl_xor(lB, 16); lB += __shfl_xor(lB, 32);

    // combine halves: fixed m_hat => partials add directly (no rescale).
    __syncthreads();
    if (half) {
        float* cb = &sm.u.comb[w4][lane][0];
        #pragma unroll
        for (int dt = 0; dt < 4; ++dt)
            #pragma unroll
            for (int r = 0; r < 4; ++r) {
                cb[dt * 4 + r]      = oA[dt][r];
                cb[16 + dt * 4 + r] = oB[dt][r];
            }
        cb[32] = lA; cb[33] = lB;
    }
    __syncthreads();
    if (half) return;

    {
        const float* cb = &sm.u.comb[w4][lane][0];
        #pragma unroll
        for (int dt = 0; dt < 4; ++dt)
            #pragma unroll
            for (int r = 0; r < 4; ++r) {
                oA[dt][r] += cb[dt * 4 + r];
                oB[dt][r] += cb[16 + dt * 4 + r];
            }
        lA += cb[32]; lB += cb[33];
    }

    // invert per-lane (row l16), then gather to C-rows (quad*4+r)
    const float iA = 1.f / lA, iB = 1.f / lB;
    float irA[4], irB[4];
    #pragma unroll
    for (int r = 0; r < 4; ++r) {
        const int src = (lane & 48) | (quad * 4 + r);
        irA[r] = __shfl(iA, src);
        irB[r] = __shfl(iB, src);
    }

    // epilogue: normalize and write
    const int h = bh & 15, b = bh >> 4;
    #pragma unroll
    for (int dt = 0; dt < 4; ++dt)
        #pragma unroll
        for (int r = 0; r < 4; ++r) {
            const int rowA = qA * 64 + w4 * 16 + quad * 4 + r;
            const int rowB = qB * 64 + w4 * 16 + quad * 4 + r;
            const int col = h * 64 + dt * 16 + l16;
            Z[((size_t)b * T_SEQ + rowA) * D_MODEL + col] = f2bf(oA[dt][r] * irA[r]);
            Z[((size_t)b * T_SEQ + rowB) * D_MODEL + col] = f2bf(oB[dt][r] * irB[r]);
        }
}

// ---------------- launcher ----------------
extern "C" void kernel_launch(void* const* d_in, const int* in_sizes, int n_in,
                              void* d_out, int out_size, void* d_ws, size_t ws_size,
                              hipStream_t stream) {
    const float* x    = (const float*)d_in[0];
    const float* cosp = (const float*)d_in[1];
    const float* sinp = (const float*)d_in[2];
    const float* Wq   = (const float*)d_in[3];
    const float* Wk   = (const float*)d_in[4];
    const float* Wv   = (const float*)d_in[5];
    const float* Wo   = (const float*)d_in[6];

    char* w = (char*)d_ws;
    unsigned short* xb  = (unsigned short*)w; w += (size_t)M_TOT * D_MODEL * 2;    // 8 MB
    unsigned short* wt  = (unsigned short*)w; w += (size_t)4 * D_MODEL * D_MODEL * 2; // 8 MB (q,k,v,o)
    unsigned short* Qb  = (unsigned short*)w; w += (size_t)M_TOT * D_MODEL * 2;    // 8 MB
    unsigned short* Kb  = (unsigned short*)w; w += (size_t)M_TOT * D_MODEL * 2;
    unsigned short* Vtb = (unsigned short*)w; w += (size_t)M_TOT * D_MODEL * 2;    // [bh][d][t]
    unsigned short* Zb  = (unsigned short*)w; w += (size_t)M_TOT * D_MODEL * 2;
    float*          Ks  = (float*)w;          w += 32 * 32 * sizeof(float);        // Ks[bh][32]

    // prep: z<4 transpose W's, z>=4 convert x (fused, one launch)
    prep_kernel<<<dim3(16, 16, 20), 256, 0, stream>>>(x, xb, Wq, Wk, Wv, Wo, wt);

    // fused QKV projection; epilogue: z=0 Q(RoPE,*0.125), z=1 K(RoPE + kmax), z=2 V(transposed)
    gemm_kernel<4, 1><<<dim3(M_TOT / 128, D_MODEL / 128, 3), 256, 0, stream>>>(
        xb, wt, (void*)Qb, cosp, sinp, Ks);

    // 512-thr blocks (8 waves), grid 512 = 2 blocks/CU, double-buffered staging
    attn_kernel<<<dim3(16, 32), 512, 0, stream>>>(Qb, Kb, Vtb, Ks, Zb);

    // out projection -> fp32 d_out
    gemm_kernel<2, 0><<<dim3(M_TOT / 64, D_MODEL / 128, 1), 256, 0, stream>>>(
        Zb, wt + (size_t)3 * D_MODEL * D_MODEL, d_out, nullptr, nullptr, nullptr);
}

// Round 11
// 205.453 us; speedup vs baseline: 1.3084x; 1.0328x over previous
//
#include <hip/hip_runtime.h>

typedef __attribute__((ext_vector_type(4))) float f32x4;
typedef __attribute__((ext_vector_type(8))) short short8;
typedef __attribute__((ext_vector_type(8))) unsigned short u16x8;
typedef __attribute__((ext_vector_type(4))) unsigned short u16x4;
typedef __attribute__((ext_vector_type(2))) unsigned int u32x2;

#define D_MODEL 1024
#define NHEADS 16
#define T_SEQ 2048
#define M_TOT 4096   // B*T

__device__ __forceinline__ unsigned short f2bf(float f) {
    union { float f; unsigned int u; } v; v.f = f;
    return (unsigned short)((v.u + 0x7fffu + ((v.u >> 16) & 1u)) >> 16);
}
__device__ __forceinline__ float bf2f(unsigned short b) {
    union { unsigned int u; float f; } v; v.u = ((unsigned int)b) << 16;
    return v.f;
}
// packed f32x2 -> bf16x2 (low = src0, high = src1)
__device__ __forceinline__ unsigned int cvtpk_bf16(float lo, float hi) {
    unsigned int r;
    asm("v_cvt_pk_bf16_f32 %0, %1, %2" : "=v"(r) : "v"(lo), "v"(hi));
    return r;
}

// volatile asm load: issue point pinned (cannot be sunk/hoisted by the compiler)
#define GLD0(dst, addr) \
    asm volatile("global_load_dwordx4 %0, %1, off" : "=v"(dst) : "v"(addr) : "memory")
// wait all asm/glds loads done, and fence the scheduler (guide rule #18)
#define WAITV0() do { asm volatile("s_waitcnt vmcnt(0)" ::: "memory"); \
                      __builtin_amdgcn_sched_barrier(0); } while (0)
// raw barrier: drain LDS only (NOT vmcnt -> in-flight prefetch survives the barrier)
#define LBAR() do { asm volatile("s_waitcnt lgkmcnt(0)" ::: "memory"); \
                    __builtin_amdgcn_s_barrier(); \
                    __builtin_amdgcn_sched_barrier(0); } while (0)

// async global -> LDS, 16B per lane, LDS dest = wave-uniform base + lane*16
#define GLDS16(gp, lp) \
    __builtin_amdgcn_global_load_lds((const __attribute__((address_space(1))) void*)(gp), \
                                     (__attribute__((address_space(3))) void*)(lp), 16, 0, 0)

// ---------------- prep: convert x fp32->bf16  +  4x W transpose->bf16 (one launch) ----------------
__global__ __launch_bounds__(256) void prep_kernel(const float* __restrict__ X,
                                                   unsigned short* __restrict__ Xb,
                                                   const float* __restrict__ W0,
                                                   const float* __restrict__ W1,
                                                   const float* __restrict__ W2,
                                                   const float* __restrict__ W3,
                                                   unsigned short* __restrict__ Wt0) {
    __shared__ float tile[64][65];
    const int z = blockIdx.z;
    if (z >= 4) {
        // convert: 16 z-slices x 256 blocks x 256 thr x 4 floats = 4096*1024
        const int blk = (z - 4) * 256 + blockIdx.y * 16 + blockIdx.x;
        const int i = (blk * 256 + threadIdx.x) * 4;
        const float4 v = *(const float4*)(X + i);
        u16x4 r;
        r.x = f2bf(v.x); r.y = f2bf(v.y); r.z = f2bf(v.z); r.w = f2bf(v.w);
        *(u16x4*)(Xb + i) = r;
        return;
    }
    const float* W = (z == 0) ? W0 : (z == 1) ? W1 : (z == 2) ? W2 : W3;
    unsigned short* Wt = Wt0 + (size_t)z * D_MODEL * D_MODEL;
    const int n0 = blockIdx.x * 64, k0 = blockIdx.y * 64;
    for (int i = threadIdx.x; i < 4096; i += 256) {
        const int r = i >> 6, c = i & 63;
        tile[r][c] = W[(size_t)(k0 + r) * D_MODEL + n0 + c];
    }
    __syncthreads();
    for (int i = threadIdx.x; i < 4096; i += 256) {
        const int r = i >> 6, c = i & 63;  // r: n-local, c: k-local
        Wt[(size_t)(n0 + r) * D_MODEL + k0 + c] = f2bf(tile[c][r]);
    }
}

// ---------------- GEMM: C = A[M][1024] @ W, Wt[n][k] pre-transposed ----------------
// R11: glds + BK=64 + PRE-SWIZZLED GLOBAL SOURCE (m173/HK s09 pattern).
// R10 post-mortem: glds with linear 64B rows made frag ds_read_b128 8-way bank
// conflicted (64B pitch => bank = slot*4 only), cancelling the staging win.
// Fix: BK=64 => 128B rows, 8 slots of 16B; chunk = 8 rows/instruction;
// LDS[r][c] = G[r][c ^ (r&7)] (global source swizzled per-lane; LDS dest linear).
// Frag read slot = (ks*4+quad) ^ (l16&7) => bank group 4*(q^(r&7)): exactly 2 rows
// per group = conflict-FREE (m136: 2-way is free). Single barrier per K-step
// (double-buffered LDS, stage->compute->vmcnt(0)->LBAR; write-after-read protected
// by previous barrier). 16 K-steps x 1 barrier (was 32 x 2). LDS 64KB -> 2 blk/CU.
// kmax fused in z==1 epilogue (norm from fp32 acc; RoPE is norm-preserving).
#define TN_G 128
#define BK_G 64

template<int MI, int OUTMODE>
__global__ __launch_bounds__(256) void gemm_kernel(
    const unsigned short* __restrict__ A,
    const unsigned short* __restrict__ Bt0,
    void* __restrict__ Cout0,
    const float* __restrict__ cosp,
    const float* __restrict__ sinp,
    float* __restrict__ Kmax)
{
    constexpr int TMc = MI * 32;
    constexpr int NCHA = TMc / 8;           // A chunks (8 rows x 128B = 1KB each)
    constexpr int NCHB = TN_G / 8;          // B chunks
    __shared__ unsigned short sA[2][TMc * 64];
    __shared__ unsigned short sB[2][TN_G * 64];

    const int tid = threadIdx.x;
    const int wid = tid >> 6;
    const int lane = tid & 63;
    const int quad = lane >> 4;
    const int l16 = lane & 15;
    const int wm = wid >> 1, wn = wid & 1;
    const int m0 = blockIdx.x * TMc, n0 = blockIdx.y * TN_G;
    const int z = blockIdx.z;
    const unsigned short* Bt = Bt0 + (size_t)z * D_MODEL * D_MODEL;
    const int r8 = lane >> 3;               // staging row within chunk (0..7)
    const int c8 = lane & 7;                // staging 16B slot (0..7)
    const int cswz = (c8 ^ r8) * 8;         // swizzled global u16 col offset
    const int rx = l16 & 7;                 // frag-read row XOR

    f32x4 acc[MI][4] = {};

    auto STAGE = [&](int b, int k0) {
        for (int ch = wid; ch < NCHA + NCHB; ch += 4) {
            if (ch < NCHA)
                GLDS16(A + (size_t)(m0 + ch * 8 + r8) * D_MODEL + k0 + cswz,
                       &sA[b][ch * 512]);
            else
                GLDS16(Bt + (size_t)(n0 + (ch - NCHA) * 8 + r8) * D_MODEL + k0 + cswz,
                       &sB[b][(ch - NCHA) * 512]);
        }
    };
    auto COMPUTE = [&](int b) {
        #pragma unroll
        for (int ks = 0; ks < 2; ++ks) {
            const int sx = ((ks * 4 + quad) ^ rx) * 8;
            short8 af[MI], bf[4];
            #pragma unroll
            for (int i = 0; i < MI; ++i)
                af[i] = *(const short8*)&sA[b][(wm * (MI * 16) + i * 16 + l16) * 64 + sx];
            #pragma unroll
            for (int i = 0; i < 4; ++i)
                bf[i] = *(const short8*)&sB[b][(wn * 64 + i * 16 + l16) * 64 + sx];
            #pragma unroll
            for (int mi = 0; mi < MI; ++mi)
                #pragma unroll
                for (int ni = 0; ni < 4; ++ni)
                    acc[mi][ni] = __builtin_amdgcn_mfma_f32_16x16x32_bf16(af[mi], bf[ni], acc[mi][ni], 0, 0, 0);
        }
    };

    // single-barrier double-buffered K loop (16 steps of BK=64)
    STAGE(0, 0);
    WAITV0();
    LBAR();
    for (int kk = 0; kk < D_MODEL / BK_G; ++kk) {
        if (kk + 1 < D_MODEL / BK_G) STAGE((kk + 1) & 1, (kk + 1) * BK_G);
        COMPUTE(kk & 1);
        WAITV0();          // own glds drained (flew during COMPUTE)
        LBAR();            // all stages visible; my frag reads done
    }

    if constexpr (OUTMODE == 0) {
        float* C = (float*)Cout0;
        #pragma unroll
        for (int mi = 0; mi < MI; ++mi) {
            const int mb = m0 + wm * (MI * 16) + mi * 16 + quad * 4;
            #pragma unroll
            for (int ni = 0; ni < 4; ++ni) {
                const int n = n0 + wn * 64 + ni * 16 + l16;
                #pragma unroll
                for (int r = 0; r < 4; ++r)
                    C[(size_t)(mb + r) * D_MODEL + n] = acc[mi][ni][r];
            }
        }
    } else {
        unsigned short* O = (unsigned short*)Cout0 + (size_t)z * M_TOT * D_MODEL;
        const int h = (n0 + wn * 64) >> 6;   // each wave's 64 cols = exactly one head
        if (z == 2) {
            // V: write transposed Vt[bh][d][t], packed u16x4 over 4 consecutive t
            #pragma unroll
            for (int mi = 0; mi < MI; ++mi) {
                const int mb = m0 + wm * (MI * 16) + mi * 16 + quad * 4;
                const int b = mb >> 11, t = mb & (T_SEQ - 1);
                #pragma unroll
                for (int ni = 0; ni < 4; ++ni) {
                    const int d = ni * 16 + l16;
                    u16x4 pk;
                    #pragma unroll
                    for (int r = 0; r < 4; ++r) pk[r] = f2bf(acc[mi][ni][r]);
                    *(u16x4*)(O + ((size_t)(b * NHEADS + h) * 64 + d) * T_SEQ + t) = pk;
                }
            }
        } else {
            if (z == 1) {
                // fused kmax: max ||k_row|| over this wave's 64 rows (one head)
                float mx = 0.f;
                #pragma unroll
                for (int mi = 0; mi < MI; ++mi)
                    #pragma unroll
                    for (int r = 0; r < 4; ++r) {
                        float s = 0.f;
                        #pragma unroll
                        for (int ni = 0; ni < 4; ++ni) s += acc[mi][ni][r] * acc[mi][ni][r];
                        s += __shfl_xor(s, 1); s += __shfl_xor(s, 2);
                        s += __shfl_xor(s, 4); s += __shfl_xor(s, 8);
                        mx = fmaxf(mx, s);
                    }
                mx = fmaxf(mx, __shfl_xor(mx, 16));
                mx = fmaxf(mx, __shfl_xor(mx, 32));
                if (lane == 0) {
                    const int b = m0 >> 11;
                    const int slot = ((m0 >> 7) & 15) * 2 + wm;
                    Kmax[(size_t)(b * NHEADS + h) * 32 + slot] = __builtin_sqrtf(mx);
                }
            }
            const float qs = (z == 0) ? 0.125f : 1.0f;   // fold 1/sqrt(64) into Q (exact in bf16)
            #pragma unroll
            for (int mi = 0; mi < MI; ++mi) {
                #pragma unroll
                for (int r = 0; r < 4; ++r) {
                    const int m = m0 + wm * (MI * 16) + mi * 16 + quad * 4 + r;
                    const int b = m >> 11, t = m & (T_SEQ - 1);
                    const size_t rowoff = ((size_t)(b * NHEADS + h) * T_SEQ + t) * 64;
                    #pragma unroll
                    for (int ni = 0; ni < 2; ++ni) {
                        const int d = ni * 16 + l16;           // 0..31
                        const float c = cosp[t * 32 + d], s = sinp[t * 32 + d];
                        const float x1 = acc[mi][ni][r], x2 = acc[mi][ni + 2][r];
                        O[rowoff + d]      = f2bf((x1 * c - x2 * s) * qs);
                        O[rowoff + d + 32] = f2bf((x1 * s + x2 * c) * qs);
                    }
                }
            }
        }
    }
}

// ---------------- flash attention (causal): SINGLE-PASS, Cauchy-Schwarz max bound ----------------
// m_hat = ||q_row|| * max_j ||k_j|| >= max s (softmax shift-invariant -> exact math).
// p = exp2(s*log2e - m_hat*log2e) <= ~1 structurally.
// R9/R10 structure (validated 57.5-58.5us): cooperative LDS staging, kv double
// buffer, one barrier/round, XOR-swizzled P, setprio around MFMA.
#define LOG2E 1.44269504f

struct AttnSmem {
    union {
        unsigned short kv[2][4][4096];  // [buf][K0,V0,K1,V1][row*64 + swz-slot*8] = 65536 B
        float comb[4][64][34];          // 34816 B: half=1 partials (O 32 + lA + lB)
    } u;
    unsigned short P[8][16 * 64];       // per-wave P tile, XOR-swizzled rows = 16384 B
};                                      // total 81920 B

__global__ __launch_bounds__(512, 2) void attn_kernel(
    const unsigned short* __restrict__ Q,    // [bh][t][64] bf16, RoPE'd, pre-scaled 0.125
    const unsigned short* __restrict__ Kg,   // [bh][t][64] bf16, RoPE'd
    const unsigned short* __restrict__ Vt,   // [bh][d][t]  bf16 (transposed)
    const float* __restrict__ Kseg,          // [bh][32] segment maxes of ||k||
    unsigned short* __restrict__ Z)          // [m][h*64+d] bf16
{
    __shared__ AttnSmem sm;

    const int tid = threadIdx.x;
    const int wid = tid >> 6;        // 0..7
    const int w4 = wid & 3;          // row-slice within q-tile
    const int half = wid >> 2;       // 0: even j, 1: odd j
    const int lane = tid & 63;
    const int quad = lane >> 4;
    const int l16 = lane & 15;
    const int srow = tid >> 3;       // staging row 0..63
    const int sslot = tid & 7;       // staging 16B slot
    const int wslot = sslot ^ (srow & 7);          // swizzled slot
    const int sxK = (quad ^ (l16 & 7)) << 3;       // kv frag-read swizzled elem offset
    const int ph8 = (l16 & 7) << 3;                // P row XOR (u16 units)

    // XCD-locality remap (bijective): flat%8 selects XCD; each XCD owns 4 whole bh.
    const int flat = blockIdx.x + 16 * blockIdx.y;     // 0..511
    const int xcd = flat & 7, idx = flat >> 3;         // idx 0..63
    const int bh = xcd * 4 + (idx & 3);                // 0..31
    const int x = idx >> 2;                            // 0..15

    const int qA = x, qB = 31 - x;       // paired q-tiles: 33 tiles/block, constant
    const int jend = 31 - x;             // kv tiles 0..jend cover both

    const unsigned short* Qp = Q + (size_t)bh * T_SEQ * 64;
    const unsigned short* Kp = Kg + (size_t)bh * T_SEQ * 64;
    const unsigned short* Vp = Vt + (size_t)bh * 64 * T_SEQ;

    // Q frags (B-operand in swapped QK): row = qt*64 + w4*16 + l16, k = ks*32 + quad*8
    short8 aqA[2], aqB[2];
    {
        const unsigned short* qr = Qp + (size_t)(qA * 64 + w4 * 16 + l16) * 64 + quad * 8;
        aqA[0] = *(const short8*)(qr);
        aqA[1] = *(const short8*)(qr + 32);
        qr = Qp + (size_t)(qB * 64 + w4 * 16 + l16) * 64 + quad * 8;
        aqB[0] = *(const short8*)(qr);
        aqB[1] = *(const short8*)(qr + 32);
    }

    // max bound: per-lane scalar for q-row l16 (swapped layout: lane = q-row)
    float kmx = 0.f;
    #pragma unroll
    for (int i = 0; i < 32; ++i) kmx = fmaxf(kmx, Kseg[bh * 32 + i]);

    float mQA, mQB;
    {
        float nqA = 0.f, nqB = 0.f;
        #pragma unroll
        for (int i = 0; i < 2; ++i)
            #pragma unroll
            for (int e = 0; e < 8; ++e) {
                const float fa = bf2f((unsigned short)aqA[i][e]);
                const float fb = bf2f((unsigned short)aqB[i][e]);
                nqA += fa * fa; nqB += fb * fb;
            }
        nqA += __shfl_xor(nqA, 16); nqA += __shfl_xor(nqA, 32);
        nqB += __shfl_xor(nqB, 16); nqB += __shfl_xor(nqB, 32);
        mQA = __builtin_sqrtf(nqA) * kmx * LOG2E;
        mQB = __builtin_sqrtf(nqB) * kmx * LOG2E;
    }

    auto tile_pack = [&](f32x4 (&s)[4], float mQ, float& lsum, bool msk,
                         unsigned short* Pw) {
        if (msk) {
            #pragma unroll
            for (int nt = 0; nt < 4; ++nt)
                #pragma unroll
                for (int r = 0; r < 4; ++r)
                    if (nt * 16 + quad * 4 + r > w4 * 16 + l16) s[nt][r] = -1e30f;
        }
        #pragma unroll
        for (int nt = 0; nt < 4; ++nt) {
            const float p0 = __builtin_exp2f(s[nt][0] * LOG2E - mQ);
            const float p1 = __builtin_exp2f(s[nt][1] * LOG2E - mQ);
            const float p2 = __builtin_exp2f(s[nt][2] * LOG2E - mQ);
            const float p3 = __builtin_exp2f(s[nt][3] * LOG2E - mQ);
            lsum += (p0 + p1) + (p2 + p3);
            const unsigned int w0 = cvtpk_bf16(p0, p1);
            const unsigned int w1 = cvtpk_bf16(p2, p3);
            *(u32x2*)&Pw[l16 * 64 + ((nt * 16 + quad * 4) ^ ph8)] = (u32x2){w0, w1};
        }
    };

    f32x4 oA[4] = {}, oB[4] = {};
    float lA = 0.f, lB = 0.f;
    unsigned short* Pw = &sm.P[wid][0];

    short8 stg[4];
    auto ISSUE = [&](int t) {   // 4 contiguous 16B loads per thread (pinned issue)
        const int j0 = 2 * t, j1 = j0 + 1;
        GLD0(stg[0], Kp + (size_t)j0 * 4096 + tid * 8);
        GLD0(stg[1], Vp + (size_t)srow * 2048 + j0 * 64 + sslot * 8);
        GLD0(stg[2], Kp + (size_t)j1 * 4096 + tid * 8);
        GLD0(stg[3], Vp + (size_t)srow * 2048 + j1 * 64 + sslot * 8);
    };
    auto WRITE = [&](int b) {   // swizzled LDS store of the staged 64B
        const int dst = srow * 64 + (wslot << 3);
        *(short8*)&sm.u.kv[b][0][dst] = stg[0];
        *(short8*)&sm.u.kv[b][1][dst] = stg[1];
        *(short8*)&sm.u.kv[b][2][dst] = stg[2];
        *(short8*)&sm.u.kv[b][3][dst] = stg[3];
    };

    auto COMPUTE = [&](int j, int b) {
        if (j > jend) return;            // last round: odd half may be inactive
        const bool doA = (j <= x);
        const unsigned short* sKb = &sm.u.kv[b][half * 2][0];
        const unsigned short* sVb = &sm.u.kv[b][half * 2 + 1][0];
        f32x4 sA[4] = {}, sB[4] = {};
        __builtin_amdgcn_s_setprio(1);
        #pragma unroll
        for (int nt = 0; nt < 4; ++nt) {
            const int rb = (nt * 16 + l16) * 64;
            const short8 k0 = *(const short8*)&sKb[rb + sxK];
            const short8 k1 = *(const short8*)&sKb[rb + (sxK ^ 32)];
            if (doA) {
                sA[nt] = __builtin_amdgcn_mfma_f32_16x16x32_bf16(k0, aqA[0], sA[nt], 0, 0, 0);
                sA[nt] = __builtin_amdgcn_mfma_f32_16x16x32_bf16(k1, aqA[1], sA[nt], 0, 0, 0);
            }
            sB[nt] = __builtin_amdgcn_mfma_f32_16x16x32_bf16(k0, aqB[0], sB[nt], 0, 0, 0);
            sB[nt] = __builtin_amdgcn_mfma_f32_16x16x32_bf16(k1, aqB[1], sB[nt], 0, 0, 0);
        }
        __builtin_amdgcn_s_setprio(0);
        short8 pfA0 = {}, pfA1 = {};
        if (doA) {
            tile_pack(sA, mQA, lA, j == x, Pw);
            asm volatile("s_waitcnt lgkmcnt(0)" ::: "memory");
            pfA0 = *(const short8*)&Pw[l16 * 64 + ((quad * 8) ^ ph8)];
            pfA1 = *(const short8*)&Pw[l16 * 64 + ((32 + quad * 8) ^ ph8)];
        }
        tile_pack(sB, mQB, lB, j == jend, Pw);
        asm volatile("s_waitcnt lgkmcnt(0)" ::: "memory");
        const short8 pfB0 = *(const short8*)&Pw[l16 * 64 + ((quad * 8) ^ ph8)];
        const short8 pfB1 = *(const short8*)&Pw[l16 * 64 + ((32 + quad * 8) ^ ph8)];
        __builtin_amdgcn_s_setprio(1);
        #pragma unroll
        for (int dt = 0; dt < 4; ++dt) {
            const int rb = (dt * 16 + l16) * 64;
            const short8 v0 = *(const short8*)&sVb[rb + sxK];
            const short8 v1 = *(const short8*)&sVb[rb + (sxK ^ 32)];
            if (doA) {
                oA[dt] = __builtin_amdgcn_mfma_f32_16x16x32_bf16(pfA0, v0, oA[dt], 0, 0, 0);
                oA[dt] = __builtin_amdgcn_mfma_f32_16x16x32_bf16(pfA1, v1, oA[dt], 0, 0, 0);
            }
            oB[dt] = __builtin_amdgcn_mfma_f32_16x16x32_bf16(pfB0, v0, oB[dt], 0, 0, 0);
            oB[dt] = __builtin_amdgcn_mfma_f32_16x16x32_bf16(pfB1, v1, oB[dt], 0, 0, 0);
        }
        __builtin_amdgcn_s_setprio(0);
    };

    // ---- single-barrier double-buffered pipeline ----
    const int nr = (jend >> 1) + 1;      // block-uniform round count
    ISSUE(0);
    WAITV0();
    WRITE(0);
    LBAR();
    for (int t = 0; t < nr; ++t) {
        const bool more = (t + 1 < nr);
        if (more) ISSUE(t + 1);          // loads fly during COMPUTE
        COMPUTE(2 * t + half, t & 1);
        if (more) {
            WAITV0();                    // staged data arrived
            WRITE((t + 1) & 1);          // other buffer: nobody reads it (ledger)
        }
        LBAR();                          // one barrier per round
    }

    // per-lane row totals (row = l16): reduce across quads
    lA += __shfl_xor(lA, 16); lA += __shfl_xor(lA, 32);
    lB += __shfl_xor(lB, 16); lB += __shfl_xor(lB, 32);

    // combine halves: fixed m_hat => partials add directly (no rescale).
    __syncthreads();
    if (half) {
        float* cb = &sm.u.comb[w4][lane][0];
        #pragma unroll
        for (int dt = 0; dt < 4; ++dt)
            #pragma unroll
            for (int r = 0; r < 4; ++r) {
                cb[dt * 4 + r]      = oA[dt][r];
                cb[16 + dt * 4 + r] = oB[dt][r];
            }
        cb[32] = lA; cb[33] = lB;
    }
    __syncthreads();
    if (half) return;

    {
        const float* cb = &sm.u.comb[w4][lane][0];
        #pragma unroll
        for (int dt = 0; dt < 4; ++dt)
            #pragma unroll
            for (int r = 0; r < 4; ++r) {
                oA[dt][r] += cb[dt * 4 + r];
                oB[dt][r] += cb[16 + dt * 4 + r];
            }
        lA += cb[32]; lB += cb[33];
    }

    // invert per-lane (row l16), then gather to C-rows (quad*4+r)
    const float iA = 1.f / lA, iB = 1.f / lB;
    float irA[4], irB[4];
    #pragma unroll
    for (int r = 0; r < 4; ++r) {
        const int src = (lane & 48) | (quad * 4 + r);
        irA[r] = __shfl(iA, src);
        irB[r] = __shfl(iB, src);
    }

    // epilogue: normalize and write
    const int h = bh & 15, b = bh >> 4;
    #pragma unroll
    for (int dt = 0; dt < 4; ++dt)
        #pragma unroll
        for (int r = 0; r < 4; ++r) {
            const int rowA = qA * 64 + w4 * 16 + quad * 4 + r;
            const int rowB = qB * 64 + w4 * 16 + quad * 4 + r;
            const int col = h * 64 + dt * 16 + l16;
            Z[((size_t)b * T_SEQ + rowA) * D_MODEL + col] = f2bf(oA[dt][r] * irA[r]);
            Z[((size_t)b * T_SEQ + rowB) * D_MODEL + col] = f2bf(oB[dt][r] * irB[r]);
        }
}

// ---------------- launcher ----------------
extern "C" void kernel_launch(void* const* d_in, const int* in_sizes, int n_in,
                              void* d_out, int out_size, void* d_ws, size_t ws_size,
                              hipStream_t stream) {
    const float* x    = (const float*)d_in[0];
    const float* cosp = (const float*)d_in[1];
    const float* sinp = (const float*)d_in[2];
    const float* Wq   = (const float*)d_in[3];
    const float* Wk   = (const float*)d_in[4];
    const float* Wv   = (const float*)d_in[5];
    const float* Wo   = (const float*)d_in[6];

    char* w = (char*)d_ws;
    unsigned short* xb  = (unsigned short*)w; w += (size_t)M_TOT * D_MODEL * 2;    // 8 MB
    unsigned short* wt  = (unsigned short*)w; w += (size_t)4 * D_MODEL * D_MODEL * 2; // 8 MB (q,k,v,o)
    unsigned short* Qb  = (unsigned short*)w; w += (size_t)M_TOT * D_MODEL * 2;    // 8 MB
    unsigned short* Kb  = (unsigned short*)w; w += (size_t)M_TOT * D_MODEL * 2;
    unsigned short* Vtb = (unsigned short*)w; w += (size_t)M_TOT * D_MODEL * 2;    // [bh][d][t]
    unsigned short* Zb  = (unsigned short*)w; w += (size_t)M_TOT * D_MODEL * 2;
    float*          Ks  = (float*)w;          w += 32 * 32 * sizeof(float);        // Ks[bh][32]

    // prep: z<4 transpose W's, z>=4 convert x (fused, one launch)
    prep_kernel<<<dim3(16, 16, 20), 256, 0, stream>>>(x, xb, Wq, Wk, Wv, Wo, wt);

    // fused QKV projection; epilogue: z=0 Q(RoPE,*0.125), z=1 K(RoPE + kmax), z=2 V(transposed)
    gemm_kernel<4, 1><<<dim3(M_TOT / 128, D_MODEL / 128, 3), 256, 0, stream>>>(
        xb, wt, (void*)Qb, cosp, sinp, Ks);

    // 512-thr blocks (8 waves), grid 512 = 2 blocks/CU, double-buffered staging
    attn_kernel<<<dim3(16, 32), 512, 0, stream>>>(Qb, Kb, Vtb, Ks, Zb);

    // out projection -> fp32 d_out (now MI=4: same MFMA density as QKV)
    gemm_kernel<4, 0><<<dim3(M_TOT / 128, D_MODEL / 128, 1), 256, 0, stream>>>(
        Zb, wt + (size_t)3 * D_MODEL * D_MODEL, d_out, nullptr, nullptr, nullptr);
}